// Round 5
// baseline (378.188 us; speedup 1.0000x reference)
//
#include <hip/hip_runtime.h>

#define HW 65536  // 256*256

typedef __bf16 bf16x8 __attribute__((ext_vector_type(8)));
typedef float f32x4 __attribute__((ext_vector_type(4)));

__device__ __forceinline__ float b2f(unsigned short u) {
    return __uint_as_float(((unsigned)u) << 16);
}
__device__ __forceinline__ unsigned short f2bu(float f) {
    unsigned u = __float_as_uint(f);
    return (unsigned short)((u + 0x7FFFu + ((u >> 16) & 1u)) >> 16);
}
// unpack a u32 holding 2 bf16 -> 2 floats (1 VALU op each)
__device__ __forceinline__ void up2(unsigned u, float& lo, float& hi) {
    lo = __uint_as_float(u << 16);
    hi = __uint_as_float(u & 0xFFFF0000u);
}

// ---------------------------------------------------------------------------
// K0: fold 6 depthwise kernels -> combined 21-tap h + 21-tap v per tensor,
// and sum the 6 biases per tensor. wcomb layout: wh1|wv1|wh2|wv2, each 64*21.
__global__ void k_prep(const float* k11, const float* k12, const float* k13,
                       const float* k14, const float* k15, const float* k16,
                       const float* k21, const float* k22, const float* k23,
                       const float* k24, const float* k25, const float* k26,
                       const float* bdw, float* wcomb, float* bias) {
    int c = threadIdx.x;
    if (c >= 64) return;
    float* wh1 = wcomb;
    float* wv1 = wcomb + 1344;
    float* wh2 = wcomb + 2688;
    float* wv2 = wcomb + 4032;
    for (int j = 0; j < 21; j++) {
        wh1[c*21+j] = k13[c*21+j];
        wv1[c*21+j] = k16[c*21+j];
        wh2[c*21+j] = k23[c*21+j];
        wv2[c*21+j] = k26[c*21+j];
    }
    for (int j = 0; j < 11; j++) {
        wh1[c*21+j+5] += k12[c*11+j];
        wv1[c*21+j+5] += k15[c*11+j];
        wh2[c*21+j+5] += k22[c*11+j];
        wv2[c*21+j+5] += k25[c*11+j];
    }
    for (int j = 0; j < 7; j++) {
        wh1[c*21+j+7] += k11[c*7+j];
        wv1[c*21+j+7] += k14[c*7+j];
        wh2[c*21+j+7] += k21[c*7+j];
        wv2[c*21+j+7] += k24[c*7+j];
    }
    float s1 = 0.f, s2 = 0.f;
    for (int i = 0; i < 6; i++) { s1 += bdw[i*64+c]; s2 += bdw[(6+i)*64+c]; }
    bias[c] = s1; bias[64+c] = s2;
}

// ---------------------------------------------------------------------------
// K1: per-pixel LayerNorm over 64 channels, fp32 in -> bf16 out (NCHW).
__global__ __launch_bounds__(256) void k_ln(
        const float* __restrict__ x1, const float* __restrict__ x2,
        const float* __restrict__ w1, const float* __restrict__ b1,
        const float* __restrict__ w2, const float* __restrict__ b2,
        unsigned short* __restrict__ o1, unsigned short* __restrict__ o2) {
    int which = blockIdx.y;
    const float* x  = which ? x2 : x1;
    const float* lw = which ? w2 : w1;
    const float* lb = which ? b2 : b1;
    unsigned short* o = which ? o2 : o1;
    int p = blockIdx.x * 256 + threadIdx.x;   // 0..262143
    int b = p >> 16, hw = p & (HW - 1);
    size_t base = (size_t)b * 64 * HW + hw;
    float v[64];
    float s = 0.f;
    #pragma unroll
    for (int c = 0; c < 64; c++) { v[c] = x[base + (size_t)c * HW]; s += v[c]; }
    float mu = s * 0.015625f;
    float s2 = 0.f;
    #pragma unroll
    for (int c = 0; c < 64; c++) { float d = v[c] - mu; s2 += d * d; }
    float rstd = rsqrtf(s2 * 0.015625f + 1e-5f);
    #pragma unroll
    for (int c = 0; c < 64; c++)
        o[base + (size_t)c * HW] = f2bu((v[c] - mu) * rstd * lw[c] + lb[c]);
}

// ---------------------------------------------------------------------------
// K2: combined depthwise conv (21-tap h + 21-tap v + bias), LDS-tiled.
__global__ __launch_bounds__(256) void k_dw(
        const unsigned short* __restrict__ in1, const unsigned short* __restrict__ in2,
        const float* __restrict__ wcomb, const float* __restrict__ bias,
        unsigned short* __restrict__ o1, unsigned short* __restrict__ o2) {
    __shared__ __align__(16) unsigned short tile[52][288];
    int which = blockIdx.y;
    const unsigned short* in = which ? in2 : in1;
    unsigned short* o = which ? o2 : o1;
    int bx = blockIdx.x;               // bc*8 + tileid
    int bc = bx >> 3, tileid = bx & 7;
    int c = bc & 63;
    int h0 = tileid * 32;
    const float* whp = wcomb + which * 2688 + c * 21;
    const float* wvp = whp + 1344;
    float wh[21], wv[21];
    #pragma unroll
    for (int j = 0; j < 21; j++) { wh[j] = whp[j]; wv[j] = wvp[j]; }
    float bs = bias[which * 64 + c];
    const unsigned short* src = in + (size_t)bc * HW;
    int tid = threadIdx.x;

    // stage 52 rows x 36 chunks (8 bf16 each); chunks 0,1,34,35 are zero pads
    for (int idx = tid; idx < 52 * 36; idx += 256) {
        int row = idx / 36, chunk = idx - row * 36;
        int grow = h0 - 10 + row;
        uint4 val = make_uint4(0u, 0u, 0u, 0u);
        if ((unsigned)grow < 256u && chunk >= 2 && chunk <= 33)
            val = *(const uint4*)(src + grow * 256 + (chunk - 2) * 8);
        *(uint4*)&tile[row][chunk * 8] = val;
    }
    __syncthreads();

    int seg = tid & 31, rgrp = tid >> 5;
    int w0 = seg * 8;
    int r0 = rgrp * 4;

    float acc[4][8];
    #pragma unroll
    for (int k = 0; k < 4; k++)
        #pragma unroll
        for (int i = 0; i < 8; i++) acc[k][i] = bs;

    #pragma unroll
    for (int rr = 0; rr < 24; rr++) {
        uint4 u = *(const uint4*)&tile[r0 + rr][16 + w0];
        float v[8];
        up2(u.x, v[0], v[1]); up2(u.y, v[2], v[3]);
        up2(u.z, v[4], v[5]); up2(u.w, v[6], v[7]);
        #pragma unroll
        for (int k = 0; k < 4; k++) {
            const int j = rr - k;
            if (j >= 0 && j < 21) {
                float wt = wv[j];
                #pragma unroll
                for (int i = 0; i < 8; i++) acc[k][i] += wt * v[i];
            }
        }
    }

    #pragma unroll
    for (int k = 0; k < 4; k++) {
        const unsigned short* rowp = &tile[r0 + k + 10][w0 + 4];
        float hv[32];
        #pragma unroll
        for (int q = 0; q < 8; q++) {
            uint2 u = *(const uint2*)(rowp + q * 4);
            up2(u.x, hv[q*4+0], hv[q*4+1]);
            up2(u.y, hv[q*4+2], hv[q*4+3]);
        }
        #pragma unroll
        for (int j = 0; j < 21; j++) {
            float wt = wh[j];
            #pragma unroll
            for (int i = 0; i < 8; i++) acc[k][i] += wt * hv[i + j + 2];
        }
    }

    size_t obase = (size_t)bc * HW;
    #pragma unroll
    for (int k = 0; k < 4; k++) {
        uint4 u;
        u.x = (unsigned)f2bu(acc[k][0]) | ((unsigned)f2bu(acc[k][1]) << 16);
        u.y = (unsigned)f2bu(acc[k][2]) | ((unsigned)f2bu(acc[k][3]) << 16);
        u.z = (unsigned)f2bu(acc[k][4]) | ((unsigned)f2bu(acc[k][5]) << 16);
        u.w = (unsigned)f2bu(acc[k][6]) | ((unsigned)f2bu(acc[k][7]) << 16);
        *(uint4*)(o + obase + (size_t)(h0 + r0 + k) * 256 + w0) = u;
    }
}

// ---------------------------------------------------------------------------
// K3: 1x1 conv (64x64) per pixel, MFMA. D[o][p] = sum_c W[o][c] X[c][p] + b.
__global__ __launch_bounds__(256) void k_pw(
        const unsigned short* __restrict__ in1, const unsigned short* __restrict__ in2,
        const float* __restrict__ wpw, const float* __restrict__ bpw,
        unsigned short* __restrict__ Eq, unsigned short* __restrict__ Fk,
        unsigned short* __restrict__ Fv) {
    __shared__ __align__(16) unsigned short Ws[64][72];
    __shared__ __align__(16) unsigned short Xs[64][260];
    __shared__ float sb[64];
    int tid = threadIdx.x;
    for (int i = tid; i < 4096; i += 256) Ws[i >> 6][i & 63] = f2bu(wpw[i]);
    if (tid < 64) sb[tid] = bpw[tid];
    int which = blockIdx.y;
    const unsigned short* in = which ? in2 : in1;
    int bx = blockIdx.x, b = bx >> 8, h = bx & 255;
    const unsigned short* src = in + (size_t)b * 64 * HW + h * 256;
    for (int i = tid; i < 2048; i += 256) {
        int c = i >> 5, ch = i & 31;
        uint4 u = *(const uint4*)(src + (size_t)c * HW + ch * 8);
        *(uint2*)&Xs[c][ch * 8]     = make_uint2(u.x, u.y);
        *(uint2*)&Xs[c][ch * 8 + 4] = make_uint2(u.z, u.w);
    }
    __syncthreads();

    int lane = tid & 63, wv = tid >> 6;
    int rA = lane & 15, g = lane >> 4;
    int p_off = wv * 64;

    f32x4 acc[4][4];
    #pragma unroll
    for (int m = 0; m < 4; m++)
        #pragma unroll
        for (int n = 0; n < 4; n++) acc[m][n] = (f32x4){0.f, 0.f, 0.f, 0.f};

    #pragma unroll
    for (int ks = 0; ks < 2; ks++) {
        int c0 = ks * 32;
        bf16x8 a[4], bb[4];
        #pragma unroll
        for (int m = 0; m < 4; m++)
            a[m] = *(const bf16x8*)&Ws[16 * m + rA][c0 + 8 * g];
        #pragma unroll
        for (int n = 0; n < 4; n++) {
            int p = p_off + 16 * n + rA;
            uint4 bu;
            bu.x = (unsigned)Xs[c0 + 8*g + 0][p] | ((unsigned)Xs[c0 + 8*g + 1][p] << 16);
            bu.y = (unsigned)Xs[c0 + 8*g + 2][p] | ((unsigned)Xs[c0 + 8*g + 3][p] << 16);
            bu.z = (unsigned)Xs[c0 + 8*g + 4][p] | ((unsigned)Xs[c0 + 8*g + 5][p] << 16);
            bu.w = (unsigned)Xs[c0 + 8*g + 6][p] | ((unsigned)Xs[c0 + 8*g + 7][p] << 16);
            bb[n] = *(bf16x8*)&bu;
        }
        #pragma unroll
        for (int m = 0; m < 4; m++)
            #pragma unroll
            for (int n = 0; n < 4; n++)
                acc[m][n] = __builtin_amdgcn_mfma_f32_16x16x32_bf16(a[m], bb[n], acc[m][n], 0, 0, 0);
    }

    unsigned short* dst = which ? Fk : Eq;
    size_t b8 = (size_t)b * 8;
    #pragma unroll
    for (int m = 0; m < 4; m++) {
        int o0 = 16 * m + 4 * g;
        int hd = o0 >> 3, cp = o0 & 7;
        #pragma unroll
        for (int n = 0; n < 4; n++) {
            int p = p_off + 16 * n + rA;       // = w
            ushort4 pk;
            #pragma unroll
            for (int r = 0; r < 4; r++)
                ((unsigned short*)&pk)[r] = f2bu(acc[m][n][r] + sb[o0 + r]);
            *(ushort4*)(dst + ((b8 + hd) * 256 + p) * 2048 + h * 8 + cp) = pk;
            if (which) {
                #pragma unroll
                for (int r = 0; r < 4; r++) {
                    int o = o0 + r;
                    Fv[((b8 + (o >> 3)) * 2048 + h * 8 + (o & 7)) * 256 + p] =
                        ((unsigned short*)&pk)[r];
                }
            }
        }
    }
}

// ---------------------------------------------------------------------------
// K4: inverse L2 norms of Q rows and K rows (1 wave per 2048-elem row).
__global__ __launch_bounds__(256) void k_norm(
        const unsigned short* __restrict__ Eq, const unsigned short* __restrict__ Fk,
        float* __restrict__ invQ, float* __restrict__ invK) {
    int lane = threadIdx.x & 63, wid = threadIdx.x >> 6;
    int row = blockIdx.x * 4 + wid;    // 0..16383
    const unsigned short* src = (row < 8192) ? Eq : Fk;
    int r = row & 8191;
    const unsigned short* p = src + (size_t)r * 2048;
    float s = 0.f;
    #pragma unroll
    for (int it = 0; it < 4; it++) {
        uint4 u = *(const uint4*)(p + it * 512 + lane * 8);
        unsigned vals[4] = {u.x, u.y, u.z, u.w};
        #pragma unroll
        for (int e = 0; e < 4; e++) {
            float lo = b2f((unsigned short)(vals[e] & 0xffffu));
            float hi = b2f((unsigned short)(vals[e] >> 16));
            s += lo * lo + hi * hi;
        }
    }
    #pragma unroll
    for (int m = 1; m < 64; m <<= 1) s += __shfl_xor(s, m, 64);
    if (lane == 0) {
        float inv = 1.f / fmaxf(sqrtf(s), 1e-12f);
        (row < 8192 ? invQ : invK)[r] = inv;
    }
}

// ---------------------------------------------------------------------------
// K5: fused attention, latency-optimized. Grid 256 = tile*32 + bh (all 8
// tiles of a bh on one XCD). 8 waves: QK^T waves own 32 S-cols; PV waves own
// 256 d. QK^T batch-unrolled x4 (24 loads in flight), PV x2 (16 loads).
// Writes attnV ONLY (no +Qn epilogue — moved to k_final as LDS RMW).
__global__ __launch_bounds__(512, 2) void k_attn(
        const unsigned short* __restrict__ Eq, const unsigned short* __restrict__ Fk,
        const unsigned short* __restrict__ Fv,
        const float* __restrict__ invQ, const float* __restrict__ invK,
        unsigned short* __restrict__ G) {
    __shared__ float Sbuf[32][264];
    __shared__ __align__(16) unsigned short Pbuf[32][256];
    __shared__ float sQ[32];
    __shared__ float sK[256];
    int bx = blockIdx.x;
    int bh = bx & 31, itile = bx >> 5, i0 = itile * 32;
    int b = bh >> 3, hd = bh & 7;
    const unsigned short* Q  = Eq + (size_t)bh * 256 * 2048;
    const unsigned short* Kp = Fk + (size_t)bh * 256 * 2048;
    const unsigned short* Vt = Fv + (size_t)bh * 2048 * 256;
    int tid = threadIdx.x, lane = tid & 63, wid = tid >> 6;
    if (tid < 32) sQ[tid] = invQ[bh * 256 + i0 + tid];
    if (tid < 256) sK[tid] = invK[bh * 256 + tid];
    __syncthreads();

    int rA = lane & 15, g = lane >> 4, kf = g * 8;

    // ---- QK^T: wave wid owns S cols [wid*32, wid*32+32) ----
    f32x4 acc[2][2];
    #pragma unroll
    for (int ib = 0; ib < 2; ib++)
        #pragma unroll
        for (int jb = 0; jb < 2; jb++) acc[ib][jb] = (f32x4){0.f, 0.f, 0.f, 0.f};

    const unsigned short* q0  = Q  + (size_t)(i0 + rA) * 2048 + kf;
    const unsigned short* q1  = q0 + 16 * 2048;
    const unsigned short* kr0 = Kp + (size_t)(wid * 32 + rA) * 2048 + kf;
    const unsigned short* kr1 = kr0 + 16 * 2048;
    for (int k0 = 0; k0 < 2048; k0 += 128) {
        bf16x8 a0[4], a1[4], b0[4], b1[4];
        #pragma unroll
        for (int s = 0; s < 4; s++) {
            int kk = k0 + s * 32;
            a0[s] = *(const bf16x8*)(q0 + kk);
            a1[s] = *(const bf16x8*)(q1 + kk);
            b0[s] = *(const bf16x8*)(kr0 + kk);
            b1[s] = *(const bf16x8*)(kr1 + kk);
        }
        #pragma unroll
        for (int s = 0; s < 4; s++) {
            acc[0][0] = __builtin_amdgcn_mfma_f32_16x16x32_bf16(a0[s], b0[s], acc[0][0], 0, 0, 0);
            acc[1][0] = __builtin_amdgcn_mfma_f32_16x16x32_bf16(a1[s], b0[s], acc[1][0], 0, 0, 0);
            acc[0][1] = __builtin_amdgcn_mfma_f32_16x16x32_bf16(a0[s], b1[s], acc[0][1], 0, 0, 0);
            acc[1][1] = __builtin_amdgcn_mfma_f32_16x16x32_bf16(a1[s], b1[s], acc[1][1], 0, 0, 0);
        }
    }
    #pragma unroll
    for (int ib = 0; ib < 2; ib++)
        #pragma unroll
        for (int jb = 0; jb < 2; jb++)
            #pragma unroll
            for (int r = 0; r < 4; r++) {
                int il = ib * 16 + g * 4 + r;
                int jl = wid * 32 + jb * 16 + rA;
                Sbuf[il][jl] = acc[ib][jb][r] * sQ[il] * sK[jl];
            }
    __syncthreads();

    // ---- softmax: 16 threads/row, col-strided; exp vals kept in regs ----
    {
        int r = tid >> 4, sub = tid & 15;
        float ev[16];
        float m = -1e30f;
        #pragma unroll
        for (int j = 0; j < 16; j++) {
            ev[j] = Sbuf[r][sub + 16 * j];
            m = fmaxf(m, ev[j]);
        }
        #pragma unroll
        for (int msk = 1; msk < 16; msk <<= 1) m = fmaxf(m, __shfl_xor(m, msk, 16));
        float s = 0.f;
        #pragma unroll
        for (int j = 0; j < 16; j++) { ev[j] = __expf(ev[j] - m); s += ev[j]; }
        #pragma unroll
        for (int msk = 1; msk < 16; msk <<= 1) s += __shfl_xor(s, msk, 16);
        float inv = 1.f / s;
        #pragma unroll
        for (int j = 0; j < 16; j++) {
            int c = sub + 16 * j;
            int unit = (c >> 3) ^ (r & 7);
            Pbuf[r][unit * 8 + (c & 7)] = f2bu(ev[j] * inv);
        }
    }
    __syncthreads();

    // ---- PV, write NCHW (attnV only); wave wid owns d in [wid*256, ...) ----
    bf16x8 pa[2][8];
    #pragma unroll
    for (int ib = 0; ib < 2; ib++)
        #pragma unroll
        for (int ks = 0; ks < 8; ks++) {
            int rr = ib * 16 + rA;
            int unit = (ks * 4 + g) ^ (rr & 7);
            pa[ib][ks] = *(const bf16x8*)&Pbuf[rr][unit * 8];
        }

    int dbase = wid * 256;
    for (int dt = 0; dt < 16; dt += 2) {
        bf16x8 vb[2][8];
        #pragma unroll
        for (int t = 0; t < 2; t++) {
            const unsigned short* vp = Vt + (size_t)(dbase + (dt + t) * 16 + rA) * 256 + kf;
            #pragma unroll
            for (int ks = 0; ks < 8; ks++)
                vb[t][ks] = *(const bf16x8*)(vp + ks * 32);
        }
        #pragma unroll
        for (int t = 0; t < 2; t++) {
            f32x4 o0 = {0.f, 0.f, 0.f, 0.f}, o1 = {0.f, 0.f, 0.f, 0.f};
            #pragma unroll
            for (int ks = 0; ks < 8; ks++) {
                o0 = __builtin_amdgcn_mfma_f32_16x16x32_bf16(pa[0][ks], vb[t][ks], o0, 0, 0, 0);
                o1 = __builtin_amdgcn_mfma_f32_16x16x32_bf16(pa[1][ks], vb[t][ks], o1, 0, 0, 0);
            }
            int d = dbase + (dt + t) * 16 + rA;
            int cpr = d & 7, hh = d >> 3;
            #pragma unroll
            for (int ib = 0; ib < 2; ib++) {
                f32x4 oa = ib ? o1 : o0;
                int ibase = i0 + ib * 16 + g * 4;
                ushort4 pk;
                #pragma unroll
                for (int r = 0; r < 4; r++)
                    ((unsigned short*)&pk)[r] = f2bu(oa[r]);
                *(ushort4*)(G + (size_t)(b * 64 + hd * 8 + cpr) * HW + hh * 256 + ibase) = pk;
            }
        }
    }
}

// ---------------------------------------------------------------------------
// K6: out = PW(attnV + Qn) + LN(x1) + LN(x2). Qn added into the staged Gs
// tile from Eq (vectorized 16-B loads) * invQ. MFMA for PW; LN fp32.
__global__ __launch_bounds__(256) void k_final(
        const unsigned short* __restrict__ G,
        const unsigned short* __restrict__ Eq, const float* __restrict__ invQ,
        const float* __restrict__ x1, const float* __restrict__ x2,
        const float* __restrict__ wpw, const float* __restrict__ bpw,
        const float* __restrict__ w1, const float* __restrict__ b1,
        const float* __restrict__ w2, const float* __restrict__ b2,
        float* __restrict__ out) {
    __shared__ __align__(16) unsigned short Ws[64][72];
    __shared__ __align__(16) unsigned short Gs[64][260];
    __shared__ __align__(16) unsigned short S12[64][260];
    __shared__ float sb[64], cw1[64], cb1[64], cw2[64], cb2[64];
    int tid = threadIdx.x;
    for (int i = tid; i < 4096; i += 256) Ws[i >> 6][i & 63] = f2bu(wpw[i]);
    if (tid < 64) {
        sb[tid] = bpw[tid];
        cw1[tid] = w1[tid]; cb1[tid] = b1[tid];
        cw2[tid] = w2[tid]; cb2[tid] = b2[tid];
    }
    int bx = blockIdx.x, b = bx >> 8, h = bx & 255;
    const unsigned short* src = G + (size_t)b * 64 * HW + h * 256;
    for (int i = tid; i < 2048; i += 256) {
        int c = i >> 5, ch = i & 31;
        uint4 u = *(const uint4*)(src + (size_t)c * HW + ch * 8);
        *(uint2*)&Gs[c][ch * 8]     = make_uint2(u.x, u.y);
        *(uint2*)&Gs[c][ch * 8 + 4] = make_uint2(u.z, u.w);
    }
    __syncthreads();
    // ---- add Qn = Eq * invQ into Gs (attn layout -> (c,w)) ----
    for (int i = tid; i < 2048; i += 256) {
        int hd = i >> 8, w = i & 255;
        int qrow = (b * 8 + hd) * 256 + w;
        uint4 qu = *(const uint4*)(Eq + (size_t)qrow * 2048 + h * 8);
        float inv = invQ[qrow];
        unsigned qs[4] = {qu.x, qu.y, qu.z, qu.w};
        #pragma unroll
        for (int e = 0; e < 4; e++) {
            float lo, hi;
            up2(qs[e], lo, hi);
            int c0 = hd * 8 + e * 2;
            Gs[c0][w]     = f2bu(b2f(Gs[c0][w]) + lo * inv);
            Gs[c0 + 1][w] = f2bu(b2f(Gs[c0 + 1][w]) + hi * inv);
        }
    }
    {
        size_t pbase = (size_t)b * 64 * HW + h * 256 + tid;
        float v[64]; float s = 0.f;
        #pragma unroll
        for (int c = 0; c < 64; c++) { v[c] = x1[pbase + (size_t)c * HW]; s += v[c]; }
        float mu = s * 0.015625f, s2 = 0.f;
        #pragma unroll
        for (int c = 0; c < 64; c++) { float d = v[c] - mu; s2 += d * d; }
        float rstd = rsqrtf(s2 * 0.015625f + 1e-5f);
        #pragma unroll
        for (int c = 0; c < 64; c++)
            S12[c][tid] = f2bu((v[c] - mu) * rstd * cw1[c] + cb1[c]);
        s = 0.f;
        #pragma unroll
        for (int c = 0; c < 64; c++) { v[c] = x2[pbase + (size_t)c * HW]; s += v[c]; }
        mu = s * 0.015625f; s2 = 0.f;
        #pragma unroll
        for (int c = 0; c < 64; c++) { float d = v[c] - mu; s2 += d * d; }
        rstd = rsqrtf(s2 * 0.015625f + 1e-5f);
        #pragma unroll
        for (int c = 0; c < 64; c++)
            S12[c][tid] = f2bu(b2f(S12[c][tid]) + (v[c] - mu) * rstd * cw2[c] + cb2[c]);
    }
    __syncthreads();

    int lane = tid & 63, wv = tid >> 6;
    int rA = lane & 15, g = lane >> 4;
    int p_off = wv * 64;

    f32x4 acc[4][4];
    #pragma unroll
    for (int m = 0; m < 4; m++)
        #pragma unroll
        for (int n = 0; n < 4; n++) acc[m][n] = (f32x4){0.f, 0.f, 0.f, 0.f};

    #pragma unroll
    for (int ks = 0; ks < 2; ks++) {
        int c0 = ks * 32;
        bf16x8 a[4], bb[4];
        #pragma unroll
        for (int m = 0; m < 4; m++)
            a[m] = *(const bf16x8*)&Ws[16 * m + rA][c0 + 8 * g];
        #pragma unroll
        for (int n = 0; n < 4; n++) {
            int p = p_off + 16 * n + rA;
            uint4 bu;
            bu.x = (unsigned)Gs[c0 + 8*g + 0][p] | ((unsigned)Gs[c0 + 8*g + 1][p] << 16);
            bu.y = (unsigned)Gs[c0 + 8*g + 2][p] | ((unsigned)Gs[c0 + 8*g + 3][p] << 16);
            bu.z = (unsigned)Gs[c0 + 8*g + 4][p] | ((unsigned)Gs[c0 + 8*g + 5][p] << 16);
            bu.w = (unsigned)Gs[c0 + 8*g + 6][p] | ((unsigned)Gs[c0 + 8*g + 7][p] << 16);
            bb[n] = *(bf16x8*)&bu;
        }
        #pragma unroll
        for (int m = 0; m < 4; m++)
            #pragma unroll
            for (int n = 0; n < 4; n++)
                acc[m][n] = __builtin_amdgcn_mfma_f32_16x16x32_bf16(a[m], bb[n], acc[m][n], 0, 0, 0);
    }

    #pragma unroll
    for (int m = 0; m < 4; m++) {
        int o0 = 16 * m + 4 * g;
        #pragma unroll
        for (int n = 0; n < 4; n++) {
            int p = p_off + 16 * n + rA;
            #pragma unroll
            for (int r = 0; r < 4; r++) {
                int o = o0 + r;
                out[(size_t)(b * 64 + o) * HW + h * 256 + p] =
                    acc[m][n][r] + sb[o] + b2f(S12[o][p]);
            }
        }
    }
}

// ---------------------------------------------------------------------------
extern "C" void kernel_launch(void* const* d_in, const int* in_sizes, int n_in,
                              void* d_out, int out_size, void* d_ws, size_t ws_size,
                              hipStream_t stream) {
    const float* x1   = (const float*)d_in[0];
    const float* x2   = (const float*)d_in[1];
    const float* ln1w = (const float*)d_in[2];
    const float* ln1b = (const float*)d_in[3];
    const float* ln2w = (const float*)d_in[4];
    const float* ln2b = (const float*)d_in[5];
    const float* bdw  = (const float*)d_in[6];
    const float* wpw  = (const float*)d_in[7];
    const float* bpw  = (const float*)d_in[8];
    const float* kk[12];
    for (int i = 0; i < 12; i++) kk[i] = (const float*)d_in[9 + i];

    char* ws = (char*)d_ws;
    float* wcomb = (float*)ws;              // 5376 floats
    float* bias  = (float*)(ws + 21504);    // 128 floats
    float* invQ  = (float*)(ws + 32768);    // 8192 floats
    float* invK  = (float*)(ws + 65536);    // 8192 floats
    const size_t SMALL = 131072;
    const size_t SZ = 33554432;             // 32 MiB = 16.7M bf16 elements

    // Slots: A = x1n -> Q, B = x2n -> K, C = V, D = attnV (all in ws).
    // dw1/dw2 live in d_out (64 MiB, dead before k_final overwrites it).
    unsigned short* A = (unsigned short*)(ws + SMALL);
    unsigned short* B = (unsigned short*)(ws + SMALL + SZ);
    unsigned short* C = (unsigned short*)(ws + SMALL + 2 * SZ);
    unsigned short* D = (unsigned short*)(ws + SMALL + 3 * SZ);
    unsigned short* dw1 = (unsigned short*)d_out;
    unsigned short* dw2 = dw1 + SZ / 2;     // element offset = 16.7M

    k_prep<<<1, 64, 0, stream>>>(kk[0], kk[1], kk[2], kk[3], kk[4], kk[5],
                                 kk[6], kk[7], kk[8], kk[9], kk[10], kk[11],
                                 bdw, wcomb, bias);
    k_ln<<<dim3(1024, 2), 256, 0, stream>>>(x1, x2, ln1w, ln1b, ln2w, ln2b, A, B);
    k_dw<<<dim3(2048, 2), 256, 0, stream>>>(A, B, wcomb, bias, dw1, dw2);
    k_pw<<<dim3(1024, 2), 256, 0, stream>>>(dw1, dw2, wpw, bpw, A, B, C);
    k_norm<<<4096, 256, 0, stream>>>(A, B, invQ, invK);
    k_attn<<<256, 512, 0, stream>>>(A, B, C, invQ, invK, D);
    k_final<<<1024, 256, 0, stream>>>(D, A, invQ, x1, x2, wpw, bpw,
                                      ln1w, ln1b, ln2w, ln2b, (float*)d_out);
}

// Round 6
// 374.140 us; speedup vs baseline: 1.0108x; 1.0108x over previous
//
#include <hip/hip_runtime.h>

#define HW 65536  // 256*256

typedef __bf16 bf16x8 __attribute__((ext_vector_type(8)));
typedef float f32x4 __attribute__((ext_vector_type(4)));

__device__ __forceinline__ float b2f(unsigned short u) {
    return __uint_as_float(((unsigned)u) << 16);
}
__device__ __forceinline__ unsigned short f2bu(float f) {
    unsigned u = __float_as_uint(f);
    return (unsigned short)((u + 0x7FFFu + ((u >> 16) & 1u)) >> 16);
}
// unpack a u32 holding 2 bf16 -> 2 floats (1 VALU op each)
__device__ __forceinline__ void up2(unsigned u, float& lo, float& hi) {
    lo = __uint_as_float(u << 16);
    hi = __uint_as_float(u & 0xFFFF0000u);
}

// ---------------------------------------------------------------------------
// K0: fold 6 depthwise kernels -> combined 21-tap h + 21-tap v per tensor,
// and sum the 6 biases per tensor. wcomb layout: wh1|wv1|wh2|wv2, each 64*21.
__global__ void k_prep(const float* k11, const float* k12, const float* k13,
                       const float* k14, const float* k15, const float* k16,
                       const float* k21, const float* k22, const float* k23,
                       const float* k24, const float* k25, const float* k26,
                       const float* bdw, float* wcomb, float* bias) {
    int c = threadIdx.x;
    if (c >= 64) return;
    float* wh1 = wcomb;
    float* wv1 = wcomb + 1344;
    float* wh2 = wcomb + 2688;
    float* wv2 = wcomb + 4032;
    for (int j = 0; j < 21; j++) {
        wh1[c*21+j] = k13[c*21+j];
        wv1[c*21+j] = k16[c*21+j];
        wh2[c*21+j] = k23[c*21+j];
        wv2[c*21+j] = k26[c*21+j];
    }
    for (int j = 0; j < 11; j++) {
        wh1[c*21+j+5] += k12[c*11+j];
        wv1[c*21+j+5] += k15[c*11+j];
        wh2[c*21+j+5] += k22[c*11+j];
        wv2[c*21+j+5] += k25[c*11+j];
    }
    for (int j = 0; j < 7; j++) {
        wh1[c*21+j+7] += k11[c*7+j];
        wv1[c*21+j+7] += k14[c*7+j];
        wh2[c*21+j+7] += k21[c*7+j];
        wv2[c*21+j+7] += k24[c*7+j];
    }
    float s1 = 0.f, s2 = 0.f;
    for (int i = 0; i < 6; i++) { s1 += bdw[i*64+c]; s2 += bdw[(6+i)*64+c]; }
    bias[c] = s1; bias[64+c] = s2;
}

// ---------------------------------------------------------------------------
// K1: per-pixel LayerNorm over 64 channels, fp32 in -> bf16 out (NCHW).
__global__ __launch_bounds__(256) void k_ln(
        const float* __restrict__ x1, const float* __restrict__ x2,
        const float* __restrict__ w1, const float* __restrict__ b1,
        const float* __restrict__ w2, const float* __restrict__ b2,
        unsigned short* __restrict__ o1, unsigned short* __restrict__ o2) {
    int which = blockIdx.y;
    const float* x  = which ? x2 : x1;
    const float* lw = which ? w2 : w1;
    const float* lb = which ? b2 : b1;
    unsigned short* o = which ? o2 : o1;
    int p = blockIdx.x * 256 + threadIdx.x;   // 0..262143
    int b = p >> 16, hw = p & (HW - 1);
    size_t base = (size_t)b * 64 * HW + hw;
    float v[64];
    float s = 0.f;
    #pragma unroll
    for (int c = 0; c < 64; c++) { v[c] = x[base + (size_t)c * HW]; s += v[c]; }
    float mu = s * 0.015625f;
    float s2 = 0.f;
    #pragma unroll
    for (int c = 0; c < 64; c++) { float d = v[c] - mu; s2 += d * d; }
    float rstd = rsqrtf(s2 * 0.015625f + 1e-5f);
    #pragma unroll
    for (int c = 0; c < 64; c++)
        o[base + (size_t)c * HW] = f2bu((v[c] - mu) * rstd * lw[c] + lb[c]);
}

// ---------------------------------------------------------------------------
// K2: combined depthwise conv (21-tap h + 21-tap v + bias), LDS-tiled.
__global__ __launch_bounds__(256) void k_dw(
        const unsigned short* __restrict__ in1, const unsigned short* __restrict__ in2,
        const float* __restrict__ wcomb, const float* __restrict__ bias,
        unsigned short* __restrict__ o1, unsigned short* __restrict__ o2) {
    __shared__ __align__(16) unsigned short tile[52][288];
    int which = blockIdx.y;
    const unsigned short* in = which ? in2 : in1;
    unsigned short* o = which ? o2 : o1;
    int bx = blockIdx.x;               // bc*8 + tileid
    int bc = bx >> 3, tileid = bx & 7;
    int c = bc & 63;
    int h0 = tileid * 32;
    const float* whp = wcomb + which * 2688 + c * 21;
    const float* wvp = whp + 1344;
    float wh[21], wv[21];
    #pragma unroll
    for (int j = 0; j < 21; j++) { wh[j] = whp[j]; wv[j] = wvp[j]; }
    float bs = bias[which * 64 + c];
    const unsigned short* src = in + (size_t)bc * HW;
    int tid = threadIdx.x;

    // stage 52 rows x 36 chunks (8 bf16 each); chunks 0,1,34,35 are zero pads
    for (int idx = tid; idx < 52 * 36; idx += 256) {
        int row = idx / 36, chunk = idx - row * 36;
        int grow = h0 - 10 + row;
        uint4 val = make_uint4(0u, 0u, 0u, 0u);
        if ((unsigned)grow < 256u && chunk >= 2 && chunk <= 33)
            val = *(const uint4*)(src + grow * 256 + (chunk - 2) * 8);
        *(uint4*)&tile[row][chunk * 8] = val;
    }
    __syncthreads();

    int seg = tid & 31, rgrp = tid >> 5;
    int w0 = seg * 8;
    int r0 = rgrp * 4;

    float acc[4][8];
    #pragma unroll
    for (int k = 0; k < 4; k++)
        #pragma unroll
        for (int i = 0; i < 8; i++) acc[k][i] = bs;

    #pragma unroll
    for (int rr = 0; rr < 24; rr++) {
        uint4 u = *(const uint4*)&tile[r0 + rr][16 + w0];
        float v[8];
        up2(u.x, v[0], v[1]); up2(u.y, v[2], v[3]);
        up2(u.z, v[4], v[5]); up2(u.w, v[6], v[7]);
        #pragma unroll
        for (int k = 0; k < 4; k++) {
            const int j = rr - k;
            if (j >= 0 && j < 21) {
                float wt = wv[j];
                #pragma unroll
                for (int i = 0; i < 8; i++) acc[k][i] += wt * v[i];
            }
        }
    }

    #pragma unroll
    for (int k = 0; k < 4; k++) {
        const unsigned short* rowp = &tile[r0 + k + 10][w0 + 4];
        float hv[32];
        #pragma unroll
        for (int q = 0; q < 8; q++) {
            uint2 u = *(const uint2*)(rowp + q * 4);
            up2(u.x, hv[q*4+0], hv[q*4+1]);
            up2(u.y, hv[q*4+2], hv[q*4+3]);
        }
        #pragma unroll
        for (int j = 0; j < 21; j++) {
            float wt = wh[j];
            #pragma unroll
            for (int i = 0; i < 8; i++) acc[k][i] += wt * hv[i + j + 2];
        }
    }

    size_t obase = (size_t)bc * HW;
    #pragma unroll
    for (int k = 0; k < 4; k++) {
        uint4 u;
        u.x = (unsigned)f2bu(acc[k][0]) | ((unsigned)f2bu(acc[k][1]) << 16);
        u.y = (unsigned)f2bu(acc[k][2]) | ((unsigned)f2bu(acc[k][3]) << 16);
        u.z = (unsigned)f2bu(acc[k][4]) | ((unsigned)f2bu(acc[k][5]) << 16);
        u.w = (unsigned)f2bu(acc[k][6]) | ((unsigned)f2bu(acc[k][7]) << 16);
        *(uint4*)(o + obase + (size_t)(h0 + r0 + k) * 256 + w0) = u;
    }
}

// ---------------------------------------------------------------------------
// K3: 1x1 conv (64x64) per pixel, MFMA. D[o][p] = sum_c W[o][c] X[c][p] + b.
__global__ __launch_bounds__(256) void k_pw(
        const unsigned short* __restrict__ in1, const unsigned short* __restrict__ in2,
        const float* __restrict__ wpw, const float* __restrict__ bpw,
        unsigned short* __restrict__ Eq, unsigned short* __restrict__ Fk,
        unsigned short* __restrict__ Fv) {
    __shared__ __align__(16) unsigned short Ws[64][72];
    __shared__ __align__(16) unsigned short Xs[64][260];
    __shared__ float sb[64];
    int tid = threadIdx.x;
    for (int i = tid; i < 4096; i += 256) Ws[i >> 6][i & 63] = f2bu(wpw[i]);
    if (tid < 64) sb[tid] = bpw[tid];
    int which = blockIdx.y;
    const unsigned short* in = which ? in2 : in1;
    int bx = blockIdx.x, b = bx >> 8, h = bx & 255;
    const unsigned short* src = in + (size_t)b * 64 * HW + h * 256;
    for (int i = tid; i < 2048; i += 256) {
        int c = i >> 5, ch = i & 31;
        uint4 u = *(const uint4*)(src + (size_t)c * HW + ch * 8);
        *(uint2*)&Xs[c][ch * 8]     = make_uint2(u.x, u.y);
        *(uint2*)&Xs[c][ch * 8 + 4] = make_uint2(u.z, u.w);
    }
    __syncthreads();

    int lane = tid & 63, wv = tid >> 6;
    int rA = lane & 15, g = lane >> 4;
    int p_off = wv * 64;

    f32x4 acc[4][4];
    #pragma unroll
    for (int m = 0; m < 4; m++)
        #pragma unroll
        for (int n = 0; n < 4; n++) acc[m][n] = (f32x4){0.f, 0.f, 0.f, 0.f};

    #pragma unroll
    for (int ks = 0; ks < 2; ks++) {
        int c0 = ks * 32;
        bf16x8 a[4], bb[4];
        #pragma unroll
        for (int m = 0; m < 4; m++)
            a[m] = *(const bf16x8*)&Ws[16 * m + rA][c0 + 8 * g];
        #pragma unroll
        for (int n = 0; n < 4; n++) {
            int p = p_off + 16 * n + rA;
            uint4 bu;
            bu.x = (unsigned)Xs[c0 + 8*g + 0][p] | ((unsigned)Xs[c0 + 8*g + 1][p] << 16);
            bu.y = (unsigned)Xs[c0 + 8*g + 2][p] | ((unsigned)Xs[c0 + 8*g + 3][p] << 16);
            bu.z = (unsigned)Xs[c0 + 8*g + 4][p] | ((unsigned)Xs[c0 + 8*g + 5][p] << 16);
            bu.w = (unsigned)Xs[c0 + 8*g + 6][p] | ((unsigned)Xs[c0 + 8*g + 7][p] << 16);
            bb[n] = *(bf16x8*)&bu;
        }
        #pragma unroll
        for (int m = 0; m < 4; m++)
            #pragma unroll
            for (int n = 0; n < 4; n++)
                acc[m][n] = __builtin_amdgcn_mfma_f32_16x16x32_bf16(a[m], bb[n], acc[m][n], 0, 0, 0);
    }

    unsigned short* dst = which ? Fk : Eq;
    size_t b8 = (size_t)b * 8;
    #pragma unroll
    for (int m = 0; m < 4; m++) {
        int o0 = 16 * m + 4 * g;
        int hd = o0 >> 3, cp = o0 & 7;
        #pragma unroll
        for (int n = 0; n < 4; n++) {
            int p = p_off + 16 * n + rA;       // = w
            ushort4 pk;
            #pragma unroll
            for (int r = 0; r < 4; r++)
                ((unsigned short*)&pk)[r] = f2bu(acc[m][n][r] + sb[o0 + r]);
            *(ushort4*)(dst + ((b8 + hd) * 256 + p) * 2048 + h * 8 + cp) = pk;
            if (which) {
                #pragma unroll
                for (int r = 0; r < 4; r++) {
                    int o = o0 + r;
                    Fv[((b8 + (o >> 3)) * 2048 + h * 8 + (o & 7)) * 256 + p] =
                        ((unsigned short*)&pk)[r];
                }
            }
        }
    }
}

// ---------------------------------------------------------------------------
// K4: inverse L2 norms of Q rows and K rows (1 wave per 2048-elem row).
__global__ __launch_bounds__(256) void k_norm(
        const unsigned short* __restrict__ Eq, const unsigned short* __restrict__ Fk,
        float* __restrict__ invQ, float* __restrict__ invK) {
    int lane = threadIdx.x & 63, wid = threadIdx.x >> 6;
    int row = blockIdx.x * 4 + wid;    // 0..16383
    const unsigned short* src = (row < 8192) ? Eq : Fk;
    int r = row & 8191;
    const unsigned short* p = src + (size_t)r * 2048;
    float s = 0.f;
    #pragma unroll
    for (int it = 0; it < 4; it++) {
        uint4 u = *(const uint4*)(p + it * 512 + lane * 8);
        unsigned vals[4] = {u.x, u.y, u.z, u.w};
        #pragma unroll
        for (int e = 0; e < 4; e++) {
            float lo = b2f((unsigned short)(vals[e] & 0xffffu));
            float hi = b2f((unsigned short)(vals[e] >> 16));
            s += lo * lo + hi * hi;
        }
    }
    #pragma unroll
    for (int m = 1; m < 64; m <<= 1) s += __shfl_xor(s, m, 64);
    if (lane == 0) {
        float inv = 1.f / fmaxf(sqrtf(s), 1e-12f);
        (row < 8192 ? invQ : invK)[r] = inv;
    }
}

// ---------------------------------------------------------------------------
// K5: fused attention, TLP version. Grid 256 = tile*32 + bh (all 8 tiles of
// a bh on XCD bh%8). 1024 threads = 16 waves (4 waves/SIMD): QK^T wave owns
// (row-half ih, 32 cols j0); PV wave owns 128 d. Softmax 32 thr/row.
// Sbuf padded to 265 (conflict-free g-groups); Pbuf XOR-swizzled for b128.
// setprio(1) around MFMA clusters (waves independent in loops -> T5).
__global__ __launch_bounds__(1024, 4) void k_attn(
        const unsigned short* __restrict__ Eq, const unsigned short* __restrict__ Fk,
        const unsigned short* __restrict__ Fv,
        const float* __restrict__ invQ, const float* __restrict__ invK,
        unsigned short* __restrict__ G) {
    __shared__ float Sbuf[32][265];
    __shared__ __align__(16) unsigned short Pbuf[32][256];
    __shared__ float sQ[32];
    __shared__ float sK[256];
    int bx = blockIdx.x;
    int bh = bx & 31, itile = bx >> 5, i0 = itile * 32;
    int b = bh >> 3, hd = bh & 7;
    const unsigned short* Q  = Eq + (size_t)bh * 256 * 2048;
    const unsigned short* Kp = Fk + (size_t)bh * 256 * 2048;
    const unsigned short* Vt = Fv + (size_t)bh * 2048 * 256;
    int tid = threadIdx.x, lane = tid & 63, wid = tid >> 6;
    if (tid < 32) sQ[tid] = invQ[bh * 256 + i0 + tid];
    if (tid >= 64 && tid < 320) sK[tid - 64] = invK[bh * 256 + tid - 64];
    __syncthreads();

    int rA = lane & 15, g = lane >> 4, kf = g * 8;
    int ih = wid & 1, j0 = (wid >> 1) * 32;

    // ---- QK^T: wave = (row-half ih, col-block j0) ----
    f32x4 acc[2];
    acc[0] = (f32x4){0.f, 0.f, 0.f, 0.f};
    acc[1] = (f32x4){0.f, 0.f, 0.f, 0.f};
    const unsigned short* qp  = Q  + (size_t)(i0 + ih * 16 + rA) * 2048 + kf;
    const unsigned short* kr0 = Kp + (size_t)(j0 + rA) * 2048 + kf;
    const unsigned short* kr1 = kr0 + 16 * 2048;
    for (int k0 = 0; k0 < 2048; k0 += 128) {
        bf16x8 a[4], b0[4], b1[4];
        #pragma unroll
        for (int s = 0; s < 4; s++) {
            int kk = k0 + s * 32;
            a[s]  = *(const bf16x8*)(qp + kk);
            b0[s] = *(const bf16x8*)(kr0 + kk);
            b1[s] = *(const bf16x8*)(kr1 + kk);
        }
        __builtin_amdgcn_s_setprio(1);
        #pragma unroll
        for (int s = 0; s < 4; s++) {
            acc[0] = __builtin_amdgcn_mfma_f32_16x16x32_bf16(a[s], b0[s], acc[0], 0, 0, 0);
            acc[1] = __builtin_amdgcn_mfma_f32_16x16x32_bf16(a[s], b1[s], acc[1], 0, 0, 0);
        }
        __builtin_amdgcn_s_setprio(0);
    }
    #pragma unroll
    for (int jb = 0; jb < 2; jb++)
        #pragma unroll
        for (int r = 0; r < 4; r++) {
            int il = ih * 16 + g * 4 + r;
            int jl = j0 + jb * 16 + rA;
            Sbuf[il][jl] = acc[jb][r] * sQ[il] * sK[jl];
        }
    __syncthreads();

    // ---- softmax: 32 threads/row, col-strided; exp vals in regs ----
    {
        int r = tid >> 5, sub = tid & 31;
        float ev[8];
        float m = -1e30f;
        #pragma unroll
        for (int j = 0; j < 8; j++) {
            ev[j] = Sbuf[r][sub + 32 * j];
            m = fmaxf(m, ev[j]);
        }
        #pragma unroll
        for (int msk = 1; msk < 32; msk <<= 1) m = fmaxf(m, __shfl_xor(m, msk, 32));
        float s = 0.f;
        #pragma unroll
        for (int j = 0; j < 8; j++) { ev[j] = __expf(ev[j] - m); s += ev[j]; }
        #pragma unroll
        for (int msk = 1; msk < 32; msk <<= 1) s += __shfl_xor(s, msk, 32);
        float inv = 1.f / s;
        #pragma unroll
        for (int j = 0; j < 8; j++) {
            int c = sub + 32 * j;
            int unit = (c >> 3) ^ (r & 7);
            Pbuf[r][unit * 8 + (c & 7)] = f2bu(ev[j] * inv);
        }
    }
    __syncthreads();

    // ---- PV + Qn, write NCHW; wave wid owns d in [wid*128, wid*128+128) ----
    bf16x8 pa[2][8];
    #pragma unroll
    for (int ib = 0; ib < 2; ib++)
        #pragma unroll
        for (int ks = 0; ks < 8; ks++) {
            int rr = ib * 16 + rA;
            int unit = (ks * 4 + g) ^ (rr & 7);
            pa[ib][ks] = *(const bf16x8*)&Pbuf[rr][unit * 8];
        }

    int dbase = wid * 128;
    for (int dt = 0; dt < 8; dt++) {
        int d0 = dbase + dt * 16;
        const unsigned short* vp = Vt + (size_t)(d0 + rA) * 256 + kf;
        bf16x8 vb[8];
        #pragma unroll
        for (int ks = 0; ks < 8; ks++)
            vb[ks] = *(const bf16x8*)(vp + ks * 32);
        f32x4 o0 = {0.f, 0.f, 0.f, 0.f}, o1 = {0.f, 0.f, 0.f, 0.f};
        __builtin_amdgcn_s_setprio(1);
        #pragma unroll
        for (int ks = 0; ks < 8; ks++) {
            o0 = __builtin_amdgcn_mfma_f32_16x16x32_bf16(pa[0][ks], vb[ks], o0, 0, 0, 0);
            o1 = __builtin_amdgcn_mfma_f32_16x16x32_bf16(pa[1][ks], vb[ks], o1, 0, 0, 0);
        }
        __builtin_amdgcn_s_setprio(0);
        int d = d0 + rA;
        int cpr = d & 7, hh = d >> 3;
        #pragma unroll
        for (int ib = 0; ib < 2; ib++) {
            f32x4 oa = ib ? o1 : o0;
            int ibase = i0 + ib * 16 + g * 4;
            ushort4 pk;
            #pragma unroll
            for (int r = 0; r < 4; r++) {
                int il = ib * 16 + g * 4 + r;
                float qv = b2f(Q[(size_t)(i0 + il) * 2048 + d]) * sQ[il];
                ((unsigned short*)&pk)[r] = f2bu(oa[r] + qv);
            }
            *(ushort4*)(G + (size_t)(b * 64 + hd * 8 + cpr) * HW + hh * 256 + ibase) = pk;
        }
    }
}

// ---------------------------------------------------------------------------
// K6: out = PW(out4) + LN(x1) + LN(x2), MFMA for PW, LN recomputed fp32.
__global__ __launch_bounds__(256) void k_final(
        const unsigned short* __restrict__ G,
        const float* __restrict__ x1, const float* __restrict__ x2,
        const float* __restrict__ wpw, const float* __restrict__ bpw,
        const float* __restrict__ w1, const float* __restrict__ b1,
        const float* __restrict__ w2, const float* __restrict__ b2,
        float* __restrict__ out) {
    __shared__ __align__(16) unsigned short Ws[64][72];
    __shared__ __align__(16) unsigned short Gs[64][260];
    __shared__ __align__(16) unsigned short S12[64][260];
    __shared__ float sb[64], cw1[64], cb1[64], cw2[64], cb2[64];
    int tid = threadIdx.x;
    for (int i = tid; i < 4096; i += 256) Ws[i >> 6][i & 63] = f2bu(wpw[i]);
    if (tid < 64) {
        sb[tid] = bpw[tid];
        cw1[tid] = w1[tid]; cb1[tid] = b1[tid];
        cw2[tid] = w2[tid]; cb2[tid] = b2[tid];
    }
    int bx = blockIdx.x, b = bx >> 8, h = bx & 255;
    const unsigned short* src = G + (size_t)b * 64 * HW + h * 256;
    for (int i = tid; i < 2048; i += 256) {
        int c = i >> 5, ch = i & 31;
        uint4 u = *(const uint4*)(src + (size_t)c * HW + ch * 8);
        *(uint2*)&Gs[c][ch * 8]     = make_uint2(u.x, u.y);
        *(uint2*)&Gs[c][ch * 8 + 4] = make_uint2(u.z, u.w);
    }
    __syncthreads();   // cw1/cb1 etc ready before stats use them
    {
        size_t pbase = (size_t)b * 64 * HW + h * 256 + tid;
        float v[64]; float s = 0.f;
        #pragma unroll
        for (int c = 0; c < 64; c++) { v[c] = x1[pbase + (size_t)c * HW]; s += v[c]; }
        float mu = s * 0.015625f, s2 = 0.f;
        #pragma unroll
        for (int c = 0; c < 64; c++) { float d = v[c] - mu; s2 += d * d; }
        float rstd = rsqrtf(s2 * 0.015625f + 1e-5f);
        #pragma unroll
        for (int c = 0; c < 64; c++)
            S12[c][tid] = f2bu((v[c] - mu) * rstd * cw1[c] + cb1[c]);
        s = 0.f;
        #pragma unroll
        for (int c = 0; c < 64; c++) { v[c] = x2[pbase + (size_t)c * HW]; s += v[c]; }
        mu = s * 0.015625f; s2 = 0.f;
        #pragma unroll
        for (int c = 0; c < 64; c++) { float d = v[c] - mu; s2 += d * d; }
        rstd = rsqrtf(s2 * 0.015625f + 1e-5f);
        #pragma unroll
        for (int c = 0; c < 64; c++)
            S12[c][tid] = f2bu(b2f(S12[c][tid]) + (v[c] - mu) * rstd * cw2[c] + cb2[c]);
    }
    __syncthreads();

    int lane = tid & 63, wv = tid >> 6;
    int rA = lane & 15, g = lane >> 4;
    int p_off = wv * 64;

    f32x4 acc[4][4];
    #pragma unroll
    for (int m = 0; m < 4; m++)
        #pragma unroll
        for (int n = 0; n < 4; n++) acc[m][n] = (f32x4){0.f, 0.f, 0.f, 0.f};

    #pragma unroll
    for (int ks = 0; ks < 2; ks++) {
        int c0 = ks * 32;
        bf16x8 a[4], bb[4];
        #pragma unroll
        for (int m = 0; m < 4; m++)
            a[m] = *(const bf16x8*)&Ws[16 * m + rA][c0 + 8 * g];
        #pragma unroll
        for (int n = 0; n < 4; n++) {
            int p = p_off + 16 * n + rA;
            uint4 bu;
            bu.x = (unsigned)Gs[c0 + 8*g + 0][p] | ((unsigned)Gs[c0 + 8*g + 1][p] << 16);
            bu.y = (unsigned)Gs[c0 + 8*g + 2][p] | ((unsigned)Gs[c0 + 8*g + 3][p] << 16);
            bu.z = (unsigned)Gs[c0 + 8*g + 4][p] | ((unsigned)Gs[c0 + 8*g + 5][p] << 16);
            bu.w = (unsigned)Gs[c0 + 8*g + 6][p] | ((unsigned)Gs[c0 + 8*g + 7][p] << 16);
            bb[n] = *(bf16x8*)&bu;
        }
        #pragma unroll
        for (int m = 0; m < 4; m++)
            #pragma unroll
            for (int n = 0; n < 4; n++)
                acc[m][n] = __builtin_amdgcn_mfma_f32_16x16x32_bf16(a[m], bb[n], acc[m][n], 0, 0, 0);
    }

    #pragma unroll
    for (int m = 0; m < 4; m++) {
        int o0 = 16 * m + 4 * g;
        #pragma unroll
        for (int n = 0; n < 4; n++) {
            int p = p_off + 16 * n + rA;
            #pragma unroll
            for (int r = 0; r < 4; r++) {
                int o = o0 + r;
                out[(size_t)(b * 64 + o) * HW + h * 256 + p] =
                    acc[m][n][r] + sb[o] + b2f(S12[o][p]);
            }
        }
    }
}

// ---------------------------------------------------------------------------
extern "C" void kernel_launch(void* const* d_in, const int* in_sizes, int n_in,
                              void* d_out, int out_size, void* d_ws, size_t ws_size,
                              hipStream_t stream) {
    const float* x1   = (const float*)d_in[0];
    const float* x2   = (const float*)d_in[1];
    const float* ln1w = (const float*)d_in[2];
    const float* ln1b = (const float*)d_in[3];
    const float* ln2w = (const float*)d_in[4];
    const float* ln2b = (const float*)d_in[5];
    const float* bdw  = (const float*)d_in[6];
    const float* wpw  = (const float*)d_in[7];
    const float* bpw  = (const float*)d_in[8];
    const float* kk[12];
    for (int i = 0; i < 12; i++) kk[i] = (const float*)d_in[9 + i];

    char* ws = (char*)d_ws;
    float* wcomb = (float*)ws;              // 5376 floats
    float* bias  = (float*)(ws + 21504);    // 128 floats
    float* invQ  = (float*)(ws + 32768);    // 8192 floats
    float* invK  = (float*)(ws + 65536);    // 8192 floats
    const size_t SMALL = 131072;
    const size_t SZ = 33554432;             // 32 MiB = 16.7M bf16 elements

    // Slots: A = x1n -> Q, B = x2n -> K, C = V, D = out4 (all in ws).
    // dw1/dw2 live in d_out (64 MiB, dead before k_final overwrites it).
    unsigned short* A = (unsigned short*)(ws + SMALL);
    unsigned short* B = (unsigned short*)(ws + SMALL + SZ);
    unsigned short* C = (unsigned short*)(ws + SMALL + 2 * SZ);
    unsigned short* D = (unsigned short*)(ws + SMALL + 3 * SZ);
    unsigned short* dw1 = (unsigned short*)d_out;
    unsigned short* dw2 = dw1 + SZ / 2;     // element offset = 16.7M

    k_prep<<<1, 64, 0, stream>>>(kk[0], kk[1], kk[2], kk[3], kk[4], kk[5],
                                 kk[6], kk[7], kk[8], kk[9], kk[10], kk[11],
                                 bdw, wcomb, bias);
    k_ln<<<dim3(1024, 2), 256, 0, stream>>>(x1, x2, ln1w, ln1b, ln2w, ln2b, A, B);
    k_dw<<<dim3(2048, 2), 256, 0, stream>>>(A, B, wcomb, bias, dw1, dw2);
    k_pw<<<dim3(1024, 2), 256, 0, stream>>>(dw1, dw2, wpw, bpw, A, B, C);
    k_norm<<<4096, 256, 0, stream>>>(A, B, invQ, invK);
    k_attn<<<256, 1024, 0, stream>>>(A, B, C, invQ, invK, D);
    k_final<<<1024, 256, 0, stream>>>(D, x1, x2, wpw, bpw,
                                      ln1w, ln1b, ln2w, ln2b, (float*)d_out);
}

// Round 7
// 356.510 us; speedup vs baseline: 1.0608x; 1.0495x over previous
//
#include <hip/hip_runtime.h>

#define HW 65536  // 256*256

typedef __bf16 bf16x8 __attribute__((ext_vector_type(8)));
typedef float f32x4 __attribute__((ext_vector_type(4)));

__device__ __forceinline__ float b2f(unsigned short u) {
    return __uint_as_float(((unsigned)u) << 16);
}
__device__ __forceinline__ unsigned short f2bu(float f) {
    unsigned u = __float_as_uint(f);
    return (unsigned short)((u + 0x7FFFu + ((u >> 16) & 1u)) >> 16);
}
// unpack a u32 holding 2 bf16 -> 2 floats (1 VALU op each)
__device__ __forceinline__ void up2(unsigned u, float& lo, float& hi) {
    lo = __uint_as_float(u << 16);
    hi = __uint_as_float(u & 0xFFFF0000u);
}

// ---------------------------------------------------------------------------
// K0: fold 6 depthwise kernels -> combined 21-tap h + 21-tap v per tensor,
// and sum the 6 biases per tensor. wcomb layout: wh1|wv1|wh2|wv2, each 64*21.
__global__ void k_prep(const float* k11, const float* k12, const float* k13,
                       const float* k14, const float* k15, const float* k16,
                       const float* k21, const float* k22, const float* k23,
                       const float* k24, const float* k25, const float* k26,
                       const float* bdw, float* wcomb, float* bias) {
    int c = threadIdx.x;
    if (c >= 64) return;
    float* wh1 = wcomb;
    float* wv1 = wcomb + 1344;
    float* wh2 = wcomb + 2688;
    float* wv2 = wcomb + 4032;
    for (int j = 0; j < 21; j++) {
        wh1[c*21+j] = k13[c*21+j];
        wv1[c*21+j] = k16[c*21+j];
        wh2[c*21+j] = k23[c*21+j];
        wv2[c*21+j] = k26[c*21+j];
    }
    for (int j = 0; j < 11; j++) {
        wh1[c*21+j+5] += k12[c*11+j];
        wv1[c*21+j+5] += k15[c*11+j];
        wh2[c*21+j+5] += k22[c*11+j];
        wv2[c*21+j+5] += k25[c*11+j];
    }
    for (int j = 0; j < 7; j++) {
        wh1[c*21+j+7] += k11[c*7+j];
        wv1[c*21+j+7] += k14[c*7+j];
        wh2[c*21+j+7] += k21[c*7+j];
        wv2[c*21+j+7] += k24[c*7+j];
    }
    float s1 = 0.f, s2 = 0.f;
    for (int i = 0; i < 6; i++) { s1 += bdw[i*64+c]; s2 += bdw[(6+i)*64+c]; }
    bias[c] = s1; bias[64+c] = s2;
}

// ---------------------------------------------------------------------------
// K1: per-pixel LayerNorm over 64 channels, fp32 in -> bf16 out (NCHW).
__global__ __launch_bounds__(256) void k_ln(
        const float* __restrict__ x1, const float* __restrict__ x2,
        const float* __restrict__ w1, const float* __restrict__ b1,
        const float* __restrict__ w2, const float* __restrict__ b2,
        unsigned short* __restrict__ o1, unsigned short* __restrict__ o2) {
    int which = blockIdx.y;
    const float* x  = which ? x2 : x1;
    const float* lw = which ? w2 : w1;
    const float* lb = which ? b2 : b1;
    unsigned short* o = which ? o2 : o1;
    int p = blockIdx.x * 256 + threadIdx.x;   // 0..262143
    int b = p >> 16, hw = p & (HW - 1);
    size_t base = (size_t)b * 64 * HW + hw;
    float v[64];
    float s = 0.f;
    #pragma unroll
    for (int c = 0; c < 64; c++) { v[c] = x[base + (size_t)c * HW]; s += v[c]; }
    float mu = s * 0.015625f;
    float s2 = 0.f;
    #pragma unroll
    for (int c = 0; c < 64; c++) { float d = v[c] - mu; s2 += d * d; }
    float rstd = rsqrtf(s2 * 0.015625f + 1e-5f);
    #pragma unroll
    for (int c = 0; c < 64; c++)
        o[base + (size_t)c * HW] = f2bu((v[c] - mu) * rstd * lw[c] + lb[c]);
}

// ---------------------------------------------------------------------------
// K2: combined depthwise conv (21-tap h + 21-tap v + bias), LDS-tiled.
__global__ __launch_bounds__(256) void k_dw(
        const unsigned short* __restrict__ in1, const unsigned short* __restrict__ in2,
        const float* __restrict__ wcomb, const float* __restrict__ bias,
        unsigned short* __restrict__ o1, unsigned short* __restrict__ o2) {
    __shared__ __align__(16) unsigned short tile[52][288];
    int which = blockIdx.y;
    const unsigned short* in = which ? in2 : in1;
    unsigned short* o = which ? o2 : o1;
    int bx = blockIdx.x;               // bc*8 + tileid
    int bc = bx >> 3, tileid = bx & 7;
    int c = bc & 63;
    int h0 = tileid * 32;
    const float* whp = wcomb + which * 2688 + c * 21;
    const float* wvp = whp + 1344;
    float wh[21], wv[21];
    #pragma unroll
    for (int j = 0; j < 21; j++) { wh[j] = whp[j]; wv[j] = wvp[j]; }
    float bs = bias[which * 64 + c];
    const unsigned short* src = in + (size_t)bc * HW;
    int tid = threadIdx.x;

    // stage 52 rows x 36 chunks (8 bf16 each); chunks 0,1,34,35 are zero pads
    for (int idx = tid; idx < 52 * 36; idx += 256) {
        int row = idx / 36, chunk = idx - row * 36;
        int grow = h0 - 10 + row;
        uint4 val = make_uint4(0u, 0u, 0u, 0u);
        if ((unsigned)grow < 256u && chunk >= 2 && chunk <= 33)
            val = *(const uint4*)(src + grow * 256 + (chunk - 2) * 8);
        *(uint4*)&tile[row][chunk * 8] = val;
    }
    __syncthreads();

    int seg = tid & 31, rgrp = tid >> 5;
    int w0 = seg * 8;
    int r0 = rgrp * 4;

    float acc[4][8];
    #pragma unroll
    for (int k = 0; k < 4; k++)
        #pragma unroll
        for (int i = 0; i < 8; i++) acc[k][i] = bs;

    #pragma unroll
    for (int rr = 0; rr < 24; rr++) {
        uint4 u = *(const uint4*)&tile[r0 + rr][16 + w0];
        float v[8];
        up2(u.x, v[0], v[1]); up2(u.y, v[2], v[3]);
        up2(u.z, v[4], v[5]); up2(u.w, v[6], v[7]);
        #pragma unroll
        for (int k = 0; k < 4; k++) {
            const int j = rr - k;
            if (j >= 0 && j < 21) {
                float wt = wv[j];
                #pragma unroll
                for (int i = 0; i < 8; i++) acc[k][i] += wt * v[i];
            }
        }
    }

    #pragma unroll
    for (int k = 0; k < 4; k++) {
        const unsigned short* rowp = &tile[r0 + k + 10][w0 + 4];
        float hv[32];
        #pragma unroll
        for (int q = 0; q < 8; q++) {
            uint2 u = *(const uint2*)(rowp + q * 4);
            up2(u.x, hv[q*4+0], hv[q*4+1]);
            up2(u.y, hv[q*4+2], hv[q*4+3]);
        }
        #pragma unroll
        for (int j = 0; j < 21; j++) {
            float wt = wh[j];
            #pragma unroll
            for (int i = 0; i < 8; i++) acc[k][i] += wt * hv[i + j + 2];
        }
    }

    size_t obase = (size_t)bc * HW;
    #pragma unroll
    for (int k = 0; k < 4; k++) {
        uint4 u;
        u.x = (unsigned)f2bu(acc[k][0]) | ((unsigned)f2bu(acc[k][1]) << 16);
        u.y = (unsigned)f2bu(acc[k][2]) | ((unsigned)f2bu(acc[k][3]) << 16);
        u.z = (unsigned)f2bu(acc[k][4]) | ((unsigned)f2bu(acc[k][5]) << 16);
        u.w = (unsigned)f2bu(acc[k][6]) | ((unsigned)f2bu(acc[k][7]) << 16);
        *(uint4*)(o + obase + (size_t)(h0 + r0 + k) * 256 + w0) = u;
    }
}

// ---------------------------------------------------------------------------
// K3: 1x1 conv (64x64) per pixel, MFMA. D[o][p] = sum_c W[o][c] X[c][p] + b.
__global__ __launch_bounds__(256) void k_pw(
        const unsigned short* __restrict__ in1, const unsigned short* __restrict__ in2,
        const float* __restrict__ wpw, const float* __restrict__ bpw,
        unsigned short* __restrict__ Eq, unsigned short* __restrict__ Fk,
        unsigned short* __restrict__ Fv) {
    __shared__ __align__(16) unsigned short Ws[64][72];
    __shared__ __align__(16) unsigned short Xs[64][260];
    __shared__ float sb[64];
    int tid = threadIdx.x;
    for (int i = tid; i < 4096; i += 256) Ws[i >> 6][i & 63] = f2bu(wpw[i]);
    if (tid < 64) sb[tid] = bpw[tid];
    int which = blockIdx.y;
    const unsigned short* in = which ? in2 : in1;
    int bx = blockIdx.x, b = bx >> 8, h = bx & 255;
    const unsigned short* src = in + (size_t)b * 64 * HW + h * 256;
    for (int i = tid; i < 2048; i += 256) {
        int c = i >> 5, ch = i & 31;
        uint4 u = *(const uint4*)(src + (size_t)c * HW + ch * 8);
        *(uint2*)&Xs[c][ch * 8]     = make_uint2(u.x, u.y);
        *(uint2*)&Xs[c][ch * 8 + 4] = make_uint2(u.z, u.w);
    }
    __syncthreads();

    int lane = tid & 63, wv = tid >> 6;
    int rA = lane & 15, g = lane >> 4;
    int p_off = wv * 64;

    f32x4 acc[4][4];
    #pragma unroll
    for (int m = 0; m < 4; m++)
        #pragma unroll
        for (int n = 0; n < 4; n++) acc[m][n] = (f32x4){0.f, 0.f, 0.f, 0.f};

    #pragma unroll
    for (int ks = 0; ks < 2; ks++) {
        int c0 = ks * 32;
        bf16x8 a[4], bb[4];
        #pragma unroll
        for (int m = 0; m < 4; m++)
            a[m] = *(const bf16x8*)&Ws[16 * m + rA][c0 + 8 * g];
        #pragma unroll
        for (int n = 0; n < 4; n++) {
            int p = p_off + 16 * n + rA;
            uint4 bu;
            bu.x = (unsigned)Xs[c0 + 8*g + 0][p] | ((unsigned)Xs[c0 + 8*g + 1][p] << 16);
            bu.y = (unsigned)Xs[c0 + 8*g + 2][p] | ((unsigned)Xs[c0 + 8*g + 3][p] << 16);
            bu.z = (unsigned)Xs[c0 + 8*g + 4][p] | ((unsigned)Xs[c0 + 8*g + 5][p] << 16);
            bu.w = (unsigned)Xs[c0 + 8*g + 6][p] | ((unsigned)Xs[c0 + 8*g + 7][p] << 16);
            bb[n] = *(bf16x8*)&bu;
        }
        #pragma unroll
        for (int m = 0; m < 4; m++)
            #pragma unroll
            for (int n = 0; n < 4; n++)
                acc[m][n] = __builtin_amdgcn_mfma_f32_16x16x32_bf16(a[m], bb[n], acc[m][n], 0, 0, 0);
    }

    unsigned short* dst = which ? Fk : Eq;
    size_t b8 = (size_t)b * 8;
    #pragma unroll
    for (int m = 0; m < 4; m++) {
        int o0 = 16 * m + 4 * g;
        int hd = o0 >> 3, cp = o0 & 7;
        #pragma unroll
        for (int n = 0; n < 4; n++) {
            int p = p_off + 16 * n + rA;       // = w
            ushort4 pk;
            #pragma unroll
            for (int r = 0; r < 4; r++)
                ((unsigned short*)&pk)[r] = f2bu(acc[m][n][r] + sb[o0 + r]);
            *(ushort4*)(dst + ((b8 + hd) * 256 + p) * 2048 + h * 8 + cp) = pk;
            if (which) {
                #pragma unroll
                for (int r = 0; r < 4; r++) {
                    int o = o0 + r;
                    Fv[((b8 + (o >> 3)) * 2048 + h * 8 + (o & 7)) * 256 + p] =
                        ((unsigned short*)&pk)[r];
                }
            }
        }
    }
}

// ---------------------------------------------------------------------------
// K4: inverse L2 norms of Q rows and K rows (1 wave per 2048-elem row).
__global__ __launch_bounds__(256) void k_norm(
        const unsigned short* __restrict__ Eq, const unsigned short* __restrict__ Fk,
        float* __restrict__ invQ, float* __restrict__ invK) {
    int lane = threadIdx.x & 63, wid = threadIdx.x >> 6;
    int row = blockIdx.x * 4 + wid;    // 0..16383
    const unsigned short* src = (row < 8192) ? Eq : Fk;
    int r = row & 8191;
    const unsigned short* p = src + (size_t)r * 2048;
    float s = 0.f;
    #pragma unroll
    for (int it = 0; it < 4; it++) {
        uint4 u = *(const uint4*)(p + it * 512 + lane * 8);
        unsigned vals[4] = {u.x, u.y, u.z, u.w};
        #pragma unroll
        for (int e = 0; e < 4; e++) {
            float lo = b2f((unsigned short)(vals[e] & 0xffffu));
            float hi = b2f((unsigned short)(vals[e] >> 16));
            s += lo * lo + hi * hi;
        }
    }
    #pragma unroll
    for (int m = 1; m < 64; m <<= 1) s += __shfl_xor(s, m, 64);
    if (lane == 0) {
        float inv = 1.f / fmaxf(sqrtf(s), 1e-12f);
        (row < 8192 ? invQ : invK)[r] = inv;
    }
}

// ---------------------------------------------------------------------------
// K5a: QK^T partial GEMM. Grid 512 = (itile*2 + ks)*32 + bh (XCD = bh%8).
// Block: 32 q-rows (itile), k-half ks (1024 of 2048). 8 waves split S-cols
// (32 each). NO LDS, NO barriers — 4096 fully independent waves.
// Writes raw-dot fp32 partials Sp[(ks*32+bh)][i][j] (into d_out, 67.1 MB).
__global__ __launch_bounds__(512, 4) void k_qkt(
        const unsigned short* __restrict__ Eq, const unsigned short* __restrict__ Fk,
        float* __restrict__ Sp) {
    int bx = blockIdx.x;
    int bh = bx & 31, t2 = bx >> 5;
    int itile = t2 >> 1, ks = t2 & 1;
    int i0 = itile * 32;
    const unsigned short* Q  = Eq + (size_t)bh * 524288 + ks * 1024;
    const unsigned short* Kp = Fk + (size_t)bh * 524288 + ks * 1024;
    int tid = threadIdx.x, lane = tid & 63, wid = tid >> 6;
    int rA = lane & 15, g = lane >> 4, kf = g * 8;

    f32x4 acc[2][2];
    #pragma unroll
    for (int ib = 0; ib < 2; ib++)
        #pragma unroll
        for (int jb = 0; jb < 2; jb++) acc[ib][jb] = (f32x4){0.f, 0.f, 0.f, 0.f};

    const unsigned short* q0  = Q  + (size_t)(i0 + rA) * 2048 + kf;
    const unsigned short* q1  = q0 + 16 * 2048;
    const unsigned short* kr0 = Kp + (size_t)(wid * 32 + rA) * 2048 + kf;
    const unsigned short* kr1 = kr0 + 16 * 2048;
    for (int k0 = 0; k0 < 1024; k0 += 128) {
        bf16x8 a0[4], a1[4], b0[4], b1[4];
        #pragma unroll
        for (int s = 0; s < 4; s++) {
            int kk = k0 + s * 32;
            a0[s] = *(const bf16x8*)(q0 + kk);
            a1[s] = *(const bf16x8*)(q1 + kk);
            b0[s] = *(const bf16x8*)(kr0 + kk);
            b1[s] = *(const bf16x8*)(kr1 + kk);
        }
        #pragma unroll
        for (int s = 0; s < 4; s++) {
            acc[0][0] = __builtin_amdgcn_mfma_f32_16x16x32_bf16(a0[s], b0[s], acc[0][0], 0, 0, 0);
            acc[1][0] = __builtin_amdgcn_mfma_f32_16x16x32_bf16(a1[s], b0[s], acc[1][0], 0, 0, 0);
            acc[0][1] = __builtin_amdgcn_mfma_f32_16x16x32_bf16(a0[s], b1[s], acc[0][1], 0, 0, 0);
            acc[1][1] = __builtin_amdgcn_mfma_f32_16x16x32_bf16(a1[s], b1[s], acc[1][1], 0, 0, 0);
        }
    }
    float* Sb = Sp + (size_t)(ks * 32 + bh) * 65536 + (size_t)i0 * 256;
    #pragma unroll
    for (int ib = 0; ib < 2; ib++)
        #pragma unroll
        for (int jb = 0; jb < 2; jb++)
            #pragma unroll
            for (int r = 0; r < 4; r++)
                Sb[(ib * 16 + g * 4 + r) * 256 + wid * 32 + jb * 16 + rA] = acc[ib][jb][r];
}

// ---------------------------------------------------------------------------
// K5b: softmax. Grid 1024 = rg*32 + bh (XCD-aligned with k_qkt's writes).
// Block: 8 rows of one bh. 32 thr/row, 8 cols each. Scale (p0+p1)*invQ*invK,
// softmax in fp32, write P bf16 [row][256].
__global__ __launch_bounds__(256) void k_smx(
        const float* __restrict__ Sp, const float* __restrict__ invQ,
        const float* __restrict__ invK, unsigned short* __restrict__ P) {
    __shared__ float sKv[256];
    int bx = blockIdx.x;
    int bh = bx & 31, rg = bx >> 5;
    int tid = threadIdx.x;
    sKv[tid] = invK[bh * 256 + tid];
    __syncthreads();
    int lr = tid >> 5, sub = tid & 31;
    int i = rg * 8 + lr;
    int R = bh * 256 + i;
    const float* p0 = Sp + (size_t)bh * 65536 + i * 256;
    const float* p1 = Sp + (size_t)(32 + bh) * 65536 + i * 256;
    float qs = invQ[R];
    int c0 = sub * 8;
    float4 a0 = *(const float4*)(p0 + c0), a1 = *(const float4*)(p0 + c0 + 4);
    float4 b0 = *(const float4*)(p1 + c0), b1 = *(const float4*)(p1 + c0 + 4);
    float v[8];
    v[0] = (a0.x + b0.x); v[1] = (a0.y + b0.y); v[2] = (a0.z + b0.z); v[3] = (a0.w + b0.w);
    v[4] = (a1.x + b1.x); v[5] = (a1.y + b1.y); v[6] = (a1.z + b1.z); v[7] = (a1.w + b1.w);
    float m = -1e30f;
    #pragma unroll
    for (int e = 0; e < 8; e++) {
        v[e] *= qs * sKv[c0 + e];
        m = fmaxf(m, v[e]);
    }
    #pragma unroll
    for (int msk = 1; msk < 32; msk <<= 1) m = fmaxf(m, __shfl_xor(m, msk, 32));
    float s = 0.f;
    #pragma unroll
    for (int e = 0; e < 8; e++) { v[e] = __expf(v[e] - m); s += v[e]; }
    #pragma unroll
    for (int msk = 1; msk < 32; msk <<= 1) s += __shfl_xor(s, msk, 32);
    float inv = 1.f / s;
    uint4 w;
    w.x = (unsigned)f2bu(v[0] * inv) | ((unsigned)f2bu(v[1] * inv) << 16);
    w.y = (unsigned)f2bu(v[2] * inv) | ((unsigned)f2bu(v[3] * inv) << 16);
    w.z = (unsigned)f2bu(v[4] * inv) | ((unsigned)f2bu(v[5] * inv) << 16);
    w.w = (unsigned)f2bu(v[6] * inv) | ((unsigned)f2bu(v[7] * inv) << 16);
    *(uint4*)(P + (size_t)R * 256 + c0) = w;
}

// ---------------------------------------------------------------------------
// K5c: PV + Qn -> out4 NCHW. Grid 512 = (itile*2 + ds)*32 + bh. Block: 32
// q-rows, d-half ds (1024 of 2048). P tile staged to swizzled LDS once;
// 8 waves then independent, each owns 128 d.
__global__ __launch_bounds__(512, 4) void k_pv(
        const unsigned short* __restrict__ P, const unsigned short* __restrict__ Fv,
        const unsigned short* __restrict__ Eq, const float* __restrict__ invQ,
        unsigned short* __restrict__ G) {
    __shared__ __align__(16) unsigned short Pb[32][256];
    __shared__ float sQ[32];
    int bx = blockIdx.x;
    int bh = bx & 31, t2 = bx >> 5;
    int itile = t2 >> 1, ds = t2 & 1;
    int i0 = itile * 32;
    int b = bh >> 3, hd = bh & 7;
    const unsigned short* Vt = Fv + (size_t)bh * 524288;
    const unsigned short* Q  = Eq + (size_t)bh * 524288;
    int tid = threadIdx.x, lane = tid & 63, wid = tid >> 6;
    // stage P[32][256] with unit-XOR swizzle
    for (int i = tid; i < 1024; i += 512) {
        int r = i >> 5, cu = i & 31;
        uint4 u = *(const uint4*)(P + (size_t)(bh * 256 + i0 + r) * 256 + cu * 8);
        int su = cu ^ (r & 7);
        *(uint4*)&Pb[r][su * 8] = u;
    }
    if (tid < 32) sQ[tid] = invQ[bh * 256 + i0 + tid];
    __syncthreads();

    int rA = lane & 15, g = lane >> 4, kf = g * 8;

    bf16x8 pa[2][8];
    #pragma unroll
    for (int ib = 0; ib < 2; ib++)
        #pragma unroll
        for (int ksl = 0; ksl < 8; ksl++) {
            int rr = ib * 16 + rA;
            int unit = (ksl * 4 + g) ^ (rr & 7);
            pa[ib][ksl] = *(const bf16x8*)&Pb[rr][unit * 8];
        }

    int dbase = ds * 1024 + wid * 128;
    for (int dt = 0; dt < 8; dt++) {
        int d0 = dbase + dt * 16;
        const unsigned short* vp = Vt + (size_t)(d0 + rA) * 256 + kf;
        bf16x8 vb[8];
        #pragma unroll
        for (int ksl = 0; ksl < 8; ksl++)
            vb[ksl] = *(const bf16x8*)(vp + ksl * 32);
        f32x4 o0 = {0.f, 0.f, 0.f, 0.f}, o1 = {0.f, 0.f, 0.f, 0.f};
        #pragma unroll
        for (int ksl = 0; ksl < 8; ksl++) {
            o0 = __builtin_amdgcn_mfma_f32_16x16x32_bf16(pa[0][ksl], vb[ksl], o0, 0, 0, 0);
            o1 = __builtin_amdgcn_mfma_f32_16x16x32_bf16(pa[1][ksl], vb[ksl], o1, 0, 0, 0);
        }
        int d = d0 + rA;
        int cpr = d & 7, hh = d >> 3;
        #pragma unroll
        for (int ib = 0; ib < 2; ib++) {
            f32x4 oa = ib ? o1 : o0;
            int ibase = i0 + ib * 16 + g * 4;
            ushort4 pk;
            #pragma unroll
            for (int r = 0; r < 4; r++) {
                int il = ib * 16 + g * 4 + r;
                float qv = b2f(Q[(size_t)(i0 + il) * 2048 + d]) * sQ[il];
                ((unsigned short*)&pk)[r] = f2bu(oa[r] + qv);
            }
            *(ushort4*)(G + (size_t)(b * 64 + hd * 8 + cpr) * HW + hh * 256 + ibase) = pk;
        }
    }
}

// ---------------------------------------------------------------------------
// K6: out = PW(out4) + LN(x1) + LN(x2), MFMA for PW, LN recomputed fp32.
__global__ __launch_bounds__(256) void k_final(
        const unsigned short* __restrict__ G,
        const float* __restrict__ x1, const float* __restrict__ x2,
        const float* __restrict__ wpw, const float* __restrict__ bpw,
        const float* __restrict__ w1, const float* __restrict__ b1,
        const float* __restrict__ w2, const float* __restrict__ b2,
        float* __restrict__ out) {
    __shared__ __align__(16) unsigned short Ws[64][72];
    __shared__ __align__(16) unsigned short Gs[64][260];
    __shared__ __align__(16) unsigned short S12[64][260];
    __shared__ float sb[64], cw1[64], cb1[64], cw2[64], cb2[64];
    int tid = threadIdx.x;
    for (int i = tid; i < 4096; i += 256) Ws[i >> 6][i & 63] = f2bu(wpw[i]);
    if (tid < 64) {
        sb[tid] = bpw[tid];
        cw1[tid] = w1[tid]; cb1[tid] = b1[tid];
        cw2[tid] = w2[tid]; cb2[tid] = b2[tid];
    }
    int bx = blockIdx.x, b = bx >> 8, h = bx & 255;
    const unsigned short* src = G + (size_t)b * 64 * HW + h * 256;
    for (int i = tid; i < 2048; i += 256) {
        int c = i >> 5, ch = i & 31;
        uint4 u = *(const uint4*)(src + (size_t)c * HW + ch * 8);
        *(uint2*)&Gs[c][ch * 8]     = make_uint2(u.x, u.y);
        *(uint2*)&Gs[c][ch * 8 + 4] = make_uint2(u.z, u.w);
    }
    __syncthreads();   // cw1/cb1 etc ready before stats use them
    {
        size_t pbase = (size_t)b * 64 * HW + h * 256 + tid;
        float v[64]; float s = 0.f;
        #pragma unroll
        for (int c = 0; c < 64; c++) { v[c] = x1[pbase + (size_t)c * HW]; s += v[c]; }
        float mu = s * 0.015625f, s2 = 0.f;
        #pragma unroll
        for (int c = 0; c < 64; c++) { float d = v[c] - mu; s2 += d * d; }
        float rstd = rsqrtf(s2 * 0.015625f + 1e-5f);
        #pragma unroll
        for (int c = 0; c < 64; c++)
            S12[c][tid] = f2bu((v[c] - mu) * rstd * cw1[c] + cb1[c]);
        s = 0.f;
        #pragma unroll
        for (int c = 0; c < 64; c++) { v[c] = x2[pbase + (size_t)c * HW]; s += v[c]; }
        mu = s * 0.015625f; s2 = 0.f;
        #pragma unroll
        for (int c = 0; c < 64; c++) { float d = v[c] - mu; s2 += d * d; }
        rstd = rsqrtf(s2 * 0.015625f + 1e-5f);
        #pragma unroll
        for (int c = 0; c < 64; c++)
            S12[c][tid] = f2bu(b2f(S12[c][tid]) + (v[c] - mu) * rstd * cw2[c] + cb2[c]);
    }
    __syncthreads();

    int lane = tid & 63, wv = tid >> 6;
    int rA = lane & 15, g = lane >> 4;
    int p_off = wv * 64;

    f32x4 acc[4][4];
    #pragma unroll
    for (int m = 0; m < 4; m++)
        #pragma unroll
        for (int n = 0; n < 4; n++) acc[m][n] = (f32x4){0.f, 0.f, 0.f, 0.f};

    #pragma unroll
    for (int ks = 0; ks < 2; ks++) {
        int c0 = ks * 32;
        bf16x8 a[4], bb[4];
        #pragma unroll
        for (int m = 0; m < 4; m++)
            a[m] = *(const bf16x8*)&Ws[16 * m + rA][c0 + 8 * g];
        #pragma unroll
        for (int n = 0; n < 4; n++) {
            int p = p_off + 16 * n + rA;
            uint4 bu;
            bu.x = (unsigned)Gs[c0 + 8*g + 0][p] | ((unsigned)Gs[c0 + 8*g + 1][p] << 16);
            bu.y = (unsigned)Gs[c0 + 8*g + 2][p] | ((unsigned)Gs[c0 + 8*g + 3][p] << 16);
            bu.z = (unsigned)Gs[c0 + 8*g + 4][p] | ((unsigned)Gs[c0 + 8*g + 5][p] << 16);
            bu.w = (unsigned)Gs[c0 + 8*g + 6][p] | ((unsigned)Gs[c0 + 8*g + 7][p] << 16);
            bb[n] = *(bf16x8*)&bu;
        }
        #pragma unroll
        for (int m = 0; m < 4; m++)
            #pragma unroll
            for (int n = 0; n < 4; n++)
                acc[m][n] = __builtin_amdgcn_mfma_f32_16x16x32_bf16(a[m], bb[n], acc[m][n], 0, 0, 0);
    }

    #pragma unroll
    for (int m = 0; m < 4; m++) {
        int o0 = 16 * m + 4 * g;
        #pragma unroll
        for (int n = 0; n < 4; n++) {
            int p = p_off + 16 * n + rA;
            #pragma unroll
            for (int r = 0; r < 4; r++) {
                int o = o0 + r;
                out[(size_t)(b * 64 + o) * HW + h * 256 + p] =
                    acc[m][n][r] + sb[o] + b2f(S12[o][p]);
            }
        }
    }
}

// ---------------------------------------------------------------------------
extern "C" void kernel_launch(void* const* d_in, const int* in_sizes, int n_in,
                              void* d_out, int out_size, void* d_ws, size_t ws_size,
                              hipStream_t stream) {
    const float* x1   = (const float*)d_in[0];
    const float* x2   = (const float*)d_in[1];
    const float* ln1w = (const float*)d_in[2];
    const float* ln1b = (const float*)d_in[3];
    const float* ln2w = (const float*)d_in[4];
    const float* ln2b = (const float*)d_in[5];
    const float* bdw  = (const float*)d_in[6];
    const float* wpw  = (const float*)d_in[7];
    const float* bpw  = (const float*)d_in[8];
    const float* kk[12];
    for (int i = 0; i < 12; i++) kk[i] = (const float*)d_in[9 + i];

    char* ws = (char*)d_ws;
    float* wcomb = (float*)ws;              // 5376 floats
    float* bias  = (float*)(ws + 21504);    // 128 floats
    float* invQ  = (float*)(ws + 32768);    // 8192 floats
    float* invK  = (float*)(ws + 65536);    // 8192 floats
    const size_t SMALL = 131072;
    const size_t SZ = 33554432;             // 32 MiB = 16.7M bf16 elements

    // Slots: A = x1n -> Q, B = x2n -> K -> P, C = V, D = out4 (all in ws).
    // dw1/dw2 live in d_out (64 MiB, dead before k_qkt). Spart (fp32, 67.1MB
    // = exactly out_size) also lives in d_out between k_qkt and k_smx; k_final
    // overwrites d_out last.
    unsigned short* A = (unsigned short*)(ws + SMALL);
    unsigned short* B = (unsigned short*)(ws + SMALL + SZ);
    unsigned short* C = (unsigned short*)(ws + SMALL + 2 * SZ);
    unsigned short* D = (unsigned short*)(ws + SMALL + 3 * SZ);
    unsigned short* dw1 = (unsigned short*)d_out;
    unsigned short* dw2 = dw1 + SZ / 2;     // element offset = 16.7M

    k_prep<<<1, 64, 0, stream>>>(kk[0], kk[1], kk[2], kk[3], kk[4], kk[5],
                                 kk[6], kk[7], kk[8], kk[9], kk[10], kk[11],
                                 bdw, wcomb, bias);
    k_ln<<<dim3(1024, 2), 256, 0, stream>>>(x1, x2, ln1w, ln1b, ln2w, ln2b, A, B);
    k_dw<<<dim3(2048, 2), 256, 0, stream>>>(A, B, wcomb, bias, dw1, dw2);
    k_pw<<<dim3(1024, 2), 256, 0, stream>>>(dw1, dw2, wpw, bpw, A, B, C);
    k_norm<<<4096, 256, 0, stream>>>(A, B, invQ, invK);
    k_qkt<<<512, 512, 0, stream>>>(A, B, (float*)d_out);
    k_smx<<<1024, 256, 0, stream>>>((float*)d_out, invQ, invK, B);
    k_pv<<<512, 512, 0, stream>>>(B, C, A, invQ, D);
    k_final<<<1024, 256, 0, stream>>>(D, x1, x2, wpw, bpw,
                                      ln1w, ln1b, ln2w, ln2b, (float*)d_out);
}

// Round 8
// 321.658 us; speedup vs baseline: 1.1757x; 1.1084x over previous
//
#include <hip/hip_runtime.h>

#define HW 65536  // 256*256

typedef __bf16 bf16x8 __attribute__((ext_vector_type(8)));
typedef float f32x4 __attribute__((ext_vector_type(4)));

__device__ __forceinline__ float b2f(unsigned short u) {
    return __uint_as_float(((unsigned)u) << 16);
}
__device__ __forceinline__ unsigned short f2bu(float f) {
    unsigned u = __float_as_uint(f);
    return (unsigned short)((u + 0x7FFFu + ((u >> 16) & 1u)) >> 16);
}
// unpack a u32 holding 2 bf16 -> 2 floats (1 VALU op each)
__device__ __forceinline__ void up2(unsigned u, float& lo, float& hi) {
    lo = __uint_as_float(u << 16);
    hi = __uint_as_float(u & 0xFFFF0000u);
}

// ---------------------------------------------------------------------------
// K0: fold 6 depthwise kernels -> combined 21-tap h + 21-tap v per tensor,
// and sum the 6 biases per tensor. wcomb layout: wh1|wv1|wh2|wv2, each 64*21.
__global__ void k_prep(const float* k11, const float* k12, const float* k13,
                       const float* k14, const float* k15, const float* k16,
                       const float* k21, const float* k22, const float* k23,
                       const float* k24, const float* k25, const float* k26,
                       const float* bdw, float* wcomb, float* bias) {
    int c = threadIdx.x;
    if (c >= 64) return;
    float* wh1 = wcomb;
    float* wv1 = wcomb + 1344;
    float* wh2 = wcomb + 2688;
    float* wv2 = wcomb + 4032;
    for (int j = 0; j < 21; j++) {
        wh1[c*21+j] = k13[c*21+j];
        wv1[c*21+j] = k16[c*21+j];
        wh2[c*21+j] = k23[c*21+j];
        wv2[c*21+j] = k26[c*21+j];
    }
    for (int j = 0; j < 11; j++) {
        wh1[c*21+j+5] += k12[c*11+j];
        wv1[c*21+j+5] += k15[c*11+j];
        wh2[c*21+j+5] += k22[c*11+j];
        wv2[c*21+j+5] += k25[c*11+j];
    }
    for (int j = 0; j < 7; j++) {
        wh1[c*21+j+7] += k11[c*7+j];
        wv1[c*21+j+7] += k14[c*7+j];
        wh2[c*21+j+7] += k21[c*7+j];
        wv2[c*21+j+7] += k24[c*7+j];
    }
    float s1 = 0.f, s2 = 0.f;
    for (int i = 0; i < 6; i++) { s1 += bdw[i*64+c]; s2 += bdw[(6+i)*64+c]; }
    bias[c] = s1; bias[64+c] = s2;
}

// ---------------------------------------------------------------------------
// K1: per-pixel LayerNorm of BOTH tensors + S12 = x1n + x2n (bf16).
// One thread per pixel; writes x1n, x2n, S12 (all NCHW bf16).
__global__ __launch_bounds__(256) void k_ln(
        const float* __restrict__ x1, const float* __restrict__ x2,
        const float* __restrict__ w1, const float* __restrict__ b1,
        const float* __restrict__ w2, const float* __restrict__ b2,
        unsigned short* __restrict__ o1, unsigned short* __restrict__ o2,
        unsigned short* __restrict__ s12) {
    int p = blockIdx.x * 256 + threadIdx.x;   // 0..262143
    int b = p >> 16, hw = p & (HW - 1);
    size_t base = (size_t)b * 64 * HW + hw;
    float v[64];
    unsigned n1[32];
    {
        float s = 0.f;
        #pragma unroll
        for (int c = 0; c < 64; c++) { v[c] = x1[base + (size_t)c * HW]; s += v[c]; }
        float mu = s * 0.015625f, s2 = 0.f;
        #pragma unroll
        for (int c = 0; c < 64; c++) { float d = v[c] - mu; s2 += d * d; }
        float rstd = rsqrtf(s2 * 0.015625f + 1e-5f);
        #pragma unroll
        for (int c2 = 0; c2 < 32; c2++) {
            unsigned short lo = f2bu((v[2*c2]   - mu) * rstd * w1[2*c2]   + b1[2*c2]);
            unsigned short hi = f2bu((v[2*c2+1] - mu) * rstd * w1[2*c2+1] + b1[2*c2+1]);
            o1[base + (size_t)(2*c2)   * HW] = lo;
            o1[base + (size_t)(2*c2+1) * HW] = hi;
            n1[c2] = (unsigned)lo | ((unsigned)hi << 16);
        }
    }
    {
        float s = 0.f;
        #pragma unroll
        for (int c = 0; c < 64; c++) { v[c] = x2[base + (size_t)c * HW]; s += v[c]; }
        float mu = s * 0.015625f, s2 = 0.f;
        #pragma unroll
        for (int c = 0; c < 64; c++) { float d = v[c] - mu; s2 += d * d; }
        float rstd = rsqrtf(s2 * 0.015625f + 1e-5f);
        #pragma unroll
        for (int c2 = 0; c2 < 32; c2++) {
            float a2 = (v[2*c2]   - mu) * rstd * w2[2*c2]   + b2[2*c2];
            float b2n = (v[2*c2+1] - mu) * rstd * w2[2*c2+1] + b2[2*c2+1];
            o2[base + (size_t)(2*c2)   * HW] = f2bu(a2);
            o2[base + (size_t)(2*c2+1) * HW] = f2bu(b2n);
            float lo, hi;
            up2(n1[c2], lo, hi);
            s12[base + (size_t)(2*c2)   * HW] = f2bu(lo + a2);
            s12[base + (size_t)(2*c2+1) * HW] = f2bu(hi + b2n);
        }
    }
}

// ---------------------------------------------------------------------------
// K2: combined depthwise conv (21-tap h + 21-tap v + bias), LDS-tiled.
__global__ __launch_bounds__(256) void k_dw(
        const unsigned short* __restrict__ in1, const unsigned short* __restrict__ in2,
        const float* __restrict__ wcomb, const float* __restrict__ bias,
        unsigned short* __restrict__ o1, unsigned short* __restrict__ o2) {
    __shared__ __align__(16) unsigned short tile[52][288];
    int which = blockIdx.y;
    const unsigned short* in = which ? in2 : in1;
    unsigned short* o = which ? o2 : o1;
    int bx = blockIdx.x;               // bc*8 + tileid
    int bc = bx >> 3, tileid = bx & 7;
    int c = bc & 63;
    int h0 = tileid * 32;
    const float* whp = wcomb + which * 2688 + c * 21;
    const float* wvp = whp + 1344;
    float wh[21], wv[21];
    #pragma unroll
    for (int j = 0; j < 21; j++) { wh[j] = whp[j]; wv[j] = wvp[j]; }
    float bs = bias[which * 64 + c];
    const unsigned short* src = in + (size_t)bc * HW;
    int tid = threadIdx.x;

    for (int idx = tid; idx < 52 * 36; idx += 256) {
        int row = idx / 36, chunk = idx - row * 36;
        int grow = h0 - 10 + row;
        uint4 val = make_uint4(0u, 0u, 0u, 0u);
        if ((unsigned)grow < 256u && chunk >= 2 && chunk <= 33)
            val = *(const uint4*)(src + grow * 256 + (chunk - 2) * 8);
        *(uint4*)&tile[row][chunk * 8] = val;
    }
    __syncthreads();

    int seg = tid & 31, rgrp = tid >> 5;
    int w0 = seg * 8;
    int r0 = rgrp * 4;

    float acc[4][8];
    #pragma unroll
    for (int k = 0; k < 4; k++)
        #pragma unroll
        for (int i = 0; i < 8; i++) acc[k][i] = bs;

    #pragma unroll
    for (int rr = 0; rr < 24; rr++) {
        uint4 u = *(const uint4*)&tile[r0 + rr][16 + w0];
        float v[8];
        up2(u.x, v[0], v[1]); up2(u.y, v[2], v[3]);
        up2(u.z, v[4], v[5]); up2(u.w, v[6], v[7]);
        #pragma unroll
        for (int k = 0; k < 4; k++) {
            const int j = rr - k;
            if (j >= 0 && j < 21) {
                float wt = wv[j];
                #pragma unroll
                for (int i = 0; i < 8; i++) acc[k][i] += wt * v[i];
            }
        }
    }

    #pragma unroll
    for (int k = 0; k < 4; k++) {
        const unsigned short* rowp = &tile[r0 + k + 10][w0 + 4];
        float hv[32];
        #pragma unroll
        for (int q = 0; q < 8; q++) {
            uint2 u = *(const uint2*)(rowp + q * 4);
            up2(u.x, hv[q*4+0], hv[q*4+1]);
            up2(u.y, hv[q*4+2], hv[q*4+3]);
        }
        #pragma unroll
        for (int j = 0; j < 21; j++) {
            float wt = wh[j];
            #pragma unroll
            for (int i = 0; i < 8; i++) acc[k][i] += wt * hv[i + j + 2];
        }
    }

    size_t obase = (size_t)bc * HW;
    #pragma unroll
    for (int k = 0; k < 4; k++) {
        uint4 u;
        u.x = (unsigned)f2bu(acc[k][0]) | ((unsigned)f2bu(acc[k][1]) << 16);
        u.y = (unsigned)f2bu(acc[k][2]) | ((unsigned)f2bu(acc[k][3]) << 16);
        u.z = (unsigned)f2bu(acc[k][4]) | ((unsigned)f2bu(acc[k][5]) << 16);
        u.w = (unsigned)f2bu(acc[k][6]) | ((unsigned)f2bu(acc[k][7]) << 16);
        *(uint4*)(o + obase + (size_t)(h0 + r0 + k) * 256 + w0) = u;
    }
}

// ---------------------------------------------------------------------------
// K3: 1x1 conv (64x64) per pixel, MFMA. Grid x remapped so the 8 blocks
// sharing each 128B output line-group (same b, same h>>3) land on the SAME
// XCD (bx%8 independent of h&7) -> per-XCD L2 can merge the 16B partial
// writes of the attn-layout rows before eviction.
__global__ __launch_bounds__(256) void k_pw(
        const unsigned short* __restrict__ in1, const unsigned short* __restrict__ in2,
        const float* __restrict__ wpw, const float* __restrict__ bpw,
        unsigned short* __restrict__ Eq, unsigned short* __restrict__ Fk,
        unsigned short* __restrict__ Fv) {
    __shared__ __align__(16) unsigned short Ws[64][72];
    __shared__ __align__(16) unsigned short Xs[64][260];
    __shared__ float sb[64];
    int tid = threadIdx.x;
    for (int i = tid; i < 4096; i += 256) Ws[i >> 6][i & 63] = f2bu(wpw[i]);
    if (tid < 64) sb[tid] = bpw[tid];
    int which = blockIdx.y;
    const unsigned short* in = which ? in2 : in1;
    int bx = blockIdx.x;
    int b = bx & 3;
    int h = ((bx >> 2) & 31) * 8 + (bx >> 7);   // same XCD for all h&7 of a group
    const unsigned short* src = in + (size_t)b * 64 * HW + h * 256;
    for (int i = tid; i < 2048; i += 256) {
        int c = i >> 5, ch = i & 31;
        uint4 u = *(const uint4*)(src + (size_t)c * HW + ch * 8);
        *(uint2*)&Xs[c][ch * 8]     = make_uint2(u.x, u.y);
        *(uint2*)&Xs[c][ch * 8 + 4] = make_uint2(u.z, u.w);
    }
    __syncthreads();

    int lane = tid & 63, wv = tid >> 6;
    int rA = lane & 15, g = lane >> 4;
    int p_off = wv * 64;

    f32x4 acc[4][4];
    #pragma unroll
    for (int m = 0; m < 4; m++)
        #pragma unroll
        for (int n = 0; n < 4; n++) acc[m][n] = (f32x4){0.f, 0.f, 0.f, 0.f};

    #pragma unroll
    for (int ks = 0; ks < 2; ks++) {
        int c0 = ks * 32;
        bf16x8 a[4], bb[4];
        #pragma unroll
        for (int m = 0; m < 4; m++)
            a[m] = *(const bf16x8*)&Ws[16 * m + rA][c0 + 8 * g];
        #pragma unroll
        for (int n = 0; n < 4; n++) {
            int p = p_off + 16 * n + rA;
            uint4 bu;
            bu.x = (unsigned)Xs[c0 + 8*g + 0][p] | ((unsigned)Xs[c0 + 8*g + 1][p] << 16);
            bu.y = (unsigned)Xs[c0 + 8*g + 2][p] | ((unsigned)Xs[c0 + 8*g + 3][p] << 16);
            bu.z = (unsigned)Xs[c0 + 8*g + 4][p] | ((unsigned)Xs[c0 + 8*g + 5][p] << 16);
            bu.w = (unsigned)Xs[c0 + 8*g + 6][p] | ((unsigned)Xs[c0 + 8*g + 7][p] << 16);
            bb[n] = *(bf16x8*)&bu;
        }
        #pragma unroll
        for (int m = 0; m < 4; m++)
            #pragma unroll
            for (int n = 0; n < 4; n++)
                acc[m][n] = __builtin_amdgcn_mfma_f32_16x16x32_bf16(a[m], bb[n], acc[m][n], 0, 0, 0);
    }

    unsigned short* dst = which ? Fk : Eq;
    size_t b8 = (size_t)b * 8;
    #pragma unroll
    for (int m = 0; m < 4; m++) {
        int o0 = 16 * m + 4 * g;
        int hd = o0 >> 3, cp = o0 & 7;
        #pragma unroll
        for (int n = 0; n < 4; n++) {
            int p = p_off + 16 * n + rA;       // = w
            ushort4 pk;
            #pragma unroll
            for (int r = 0; r < 4; r++)
                ((unsigned short*)&pk)[r] = f2bu(acc[m][n][r] + sb[o0 + r]);
            *(ushort4*)(dst + ((b8 + hd) * 256 + p) * 2048 + h * 8 + cp) = pk;
            if (which) {
                #pragma unroll
                for (int r = 0; r < 4; r++) {
                    int o = o0 + r;
                    Fv[((b8 + (o >> 3)) * 2048 + h * 8 + (o & 7)) * 256 + p] =
                        ((unsigned short*)&pk)[r];
                }
            }
        }
    }
}

// ---------------------------------------------------------------------------
// K4: inverse L2 norms of Q rows and K rows (1 wave per 2048-elem row).
__global__ __launch_bounds__(256) void k_norm(
        const unsigned short* __restrict__ Eq, const unsigned short* __restrict__ Fk,
        float* __restrict__ invQ, float* __restrict__ invK) {
    int lane = threadIdx.x & 63, wid = threadIdx.x >> 6;
    int row = blockIdx.x * 4 + wid;    // 0..16383
    const unsigned short* src = (row < 8192) ? Eq : Fk;
    int r = row & 8191;
    const unsigned short* p = src + (size_t)r * 2048;
    float s = 0.f;
    #pragma unroll
    for (int it = 0; it < 4; it++) {
        uint4 u = *(const uint4*)(p + it * 512 + lane * 8);
        unsigned vals[4] = {u.x, u.y, u.z, u.w};
        #pragma unroll
        for (int e = 0; e < 4; e++) {
            float lo = b2f((unsigned short)(vals[e] & 0xffffu));
            float hi = b2f((unsigned short)(vals[e] >> 16));
            s += lo * lo + hi * hi;
        }
    }
    #pragma unroll
    for (int m = 1; m < 64; m <<= 1) s += __shfl_xor(s, m, 64);
    if (lane == 0) {
        float inv = 1.f / fmaxf(sqrtf(s), 1e-12f);
        (row < 8192 ? invQ : invK)[r] = inv;
    }
}

// ---------------------------------------------------------------------------
// K5a: QK^T partial GEMM. Grid 512 = (itile*2 + ks)*32 + bh (XCD = bh%8).
// 8 waves split S-cols; no LDS, no barriers. Writes fp32 partials to Sp.
__global__ __launch_bounds__(512, 4) void k_qkt(
        const unsigned short* __restrict__ Eq, const unsigned short* __restrict__ Fk,
        float* __restrict__ Sp) {
    int bx = blockIdx.x;
    int bh = bx & 31, t2 = bx >> 5;
    int itile = t2 >> 1, ks = t2 & 1;
    int i0 = itile * 32;
    const unsigned short* Q  = Eq + (size_t)bh * 524288 + ks * 1024;
    const unsigned short* Kp = Fk + (size_t)bh * 524288 + ks * 1024;
    int tid = threadIdx.x, lane = tid & 63, wid = tid >> 6;
    int rA = lane & 15, g = lane >> 4, kf = g * 8;

    f32x4 acc[2][2];
    #pragma unroll
    for (int ib = 0; ib < 2; ib++)
        #pragma unroll
        for (int jb = 0; jb < 2; jb++) acc[ib][jb] = (f32x4){0.f, 0.f, 0.f, 0.f};

    const unsigned short* q0  = Q  + (size_t)(i0 + rA) * 2048 + kf;
    const unsigned short* q1  = q0 + 16 * 2048;
    const unsigned short* kr0 = Kp + (size_t)(wid * 32 + rA) * 2048 + kf;
    const unsigned short* kr1 = kr0 + 16 * 2048;
    for (int k0 = 0; k0 < 1024; k0 += 128) {
        bf16x8 a0[4], a1[4], b0[4], b1[4];
        #pragma unroll
        for (int s = 0; s < 4; s++) {
            int kk = k0 + s * 32;
            a0[s] = *(const bf16x8*)(q0 + kk);
            a1[s] = *(const bf16x8*)(q1 + kk);
            b0[s] = *(const bf16x8*)(kr0 + kk);
            b1[s] = *(const bf16x8*)(kr1 + kk);
        }
        #pragma unroll
        for (int s = 0; s < 4; s++) {
            acc[0][0] = __builtin_amdgcn_mfma_f32_16x16x32_bf16(a0[s], b0[s], acc[0][0], 0, 0, 0);
            acc[1][0] = __builtin_amdgcn_mfma_f32_16x16x32_bf16(a1[s], b0[s], acc[1][0], 0, 0, 0);
            acc[0][1] = __builtin_amdgcn_mfma_f32_16x16x32_bf16(a0[s], b1[s], acc[0][1], 0, 0, 0);
            acc[1][1] = __builtin_amdgcn_mfma_f32_16x16x32_bf16(a1[s], b1[s], acc[1][1], 0, 0, 0);
        }
    }
    float* Sb = Sp + (size_t)(ks * 32 + bh) * 65536 + (size_t)i0 * 256;
    #pragma unroll
    for (int ib = 0; ib < 2; ib++)
        #pragma unroll
        for (int jb = 0; jb < 2; jb++)
            #pragma unroll
            for (int r = 0; r < 4; r++)
                Sb[(ib * 16 + g * 4 + r) * 256 + wid * 32 + jb * 16 + rA] = acc[ib][jb][r];
}

// ---------------------------------------------------------------------------
// K5b: softmax. Grid 1024 = rg*32 + bh. Scale (p0+p1)*invQ*invK, softmax,
// write P bf16.
__global__ __launch_bounds__(256) void k_smx(
        const float* __restrict__ Sp, const float* __restrict__ invQ,
        const float* __restrict__ invK, unsigned short* __restrict__ P) {
    __shared__ float sKv[256];
    int bx = blockIdx.x;
    int bh = bx & 31, rg = bx >> 5;
    int tid = threadIdx.x;
    sKv[tid] = invK[bh * 256 + tid];
    __syncthreads();
    int lr = tid >> 5, sub = tid & 31;
    int i = rg * 8 + lr;
    int R = bh * 256 + i;
    const float* p0 = Sp + (size_t)bh * 65536 + i * 256;
    const float* p1 = Sp + (size_t)(32 + bh) * 65536 + i * 256;
    float qs = invQ[R];
    int c0 = sub * 8;
    float4 a0 = *(const float4*)(p0 + c0), a1 = *(const float4*)(p0 + c0 + 4);
    float4 b0 = *(const float4*)(p1 + c0), b1 = *(const float4*)(p1 + c0 + 4);
    float v[8];
    v[0] = (a0.x + b0.x); v[1] = (a0.y + b0.y); v[2] = (a0.z + b0.z); v[3] = (a0.w + b0.w);
    v[4] = (a1.x + b1.x); v[5] = (a1.y + b1.y); v[6] = (a1.z + b1.z); v[7] = (a1.w + b1.w);
    float m = -1e30f;
    #pragma unroll
    for (int e = 0; e < 8; e++) {
        v[e] *= qs * sKv[c0 + e];
        m = fmaxf(m, v[e]);
    }
    #pragma unroll
    for (int msk = 1; msk < 32; msk <<= 1) m = fmaxf(m, __shfl_xor(m, msk, 32));
    float s = 0.f;
    #pragma unroll
    for (int e = 0; e < 8; e++) { v[e] = __expf(v[e] - m); s += v[e]; }
    #pragma unroll
    for (int msk = 1; msk < 32; msk <<= 1) s += __shfl_xor(s, msk, 32);
    float inv = 1.f / s;
    uint4 w;
    w.x = (unsigned)f2bu(v[0] * inv) | ((unsigned)f2bu(v[1] * inv) << 16);
    w.y = (unsigned)f2bu(v[2] * inv) | ((unsigned)f2bu(v[3] * inv) << 16);
    w.z = (unsigned)f2bu(v[4] * inv) | ((unsigned)f2bu(v[5] * inv) << 16);
    w.w = (unsigned)f2bu(v[6] * inv) | ((unsigned)f2bu(v[7] * inv) << 16);
    *(uint4*)(P + (size_t)R * 256 + c0) = w;
}

// ---------------------------------------------------------------------------
// K5c: PV + Qn -> out4 NCHW. Grid 512 = (itile*2 + ds)*32 + bh. P staged to
// swizzled LDS; Q-tile (32 x 1024) staged coalesced to LDS for the epilogue.
__global__ __launch_bounds__(512, 4) void k_pv(
        const unsigned short* __restrict__ P, const unsigned short* __restrict__ Fv,
        const unsigned short* __restrict__ Eq, const float* __restrict__ invQ,
        unsigned short* __restrict__ G) {
    __shared__ __align__(16) unsigned short Pb[32][256];
    __shared__ __align__(16) unsigned short Qs[32][1024];
    __shared__ float sQ[32];
    int bx = blockIdx.x;
    int bh = bx & 31, t2 = bx >> 5;
    int itile = t2 >> 1, ds = t2 & 1;
    int i0 = itile * 32;
    int b = bh >> 3, hd = bh & 7;
    const unsigned short* Vt = Fv + (size_t)bh * 524288;
    int tid = threadIdx.x, lane = tid & 63, wid = tid >> 6;
    // stage P[32][256] with unit-XOR swizzle
    for (int i = tid; i < 1024; i += 512) {
        int r = i >> 5, cu = i & 31;
        uint4 u = *(const uint4*)(P + (size_t)(bh * 256 + i0 + r) * 256 + cu * 8);
        int su = cu ^ (r & 7);
        *(uint4*)&Pb[r][su * 8] = u;
    }
    // stage Q tile [32 rows][1024 d] coalesced
    for (int i = tid; i < 4096; i += 512) {
        int r = i >> 7, cu = i & 127;
        *(uint4*)&Qs[r][cu * 8] =
            *(const uint4*)(Eq + (size_t)(bh * 256 + i0 + r) * 2048 + ds * 1024 + cu * 8);
    }
    if (tid < 32) sQ[tid] = invQ[bh * 256 + i0 + tid];
    __syncthreads();

    int rA = lane & 15, g = lane >> 4, kf = g * 8;

    bf16x8 pa[2][8];
    #pragma unroll
    for (int ib = 0; ib < 2; ib++)
        #pragma unroll
        for (int ksl = 0; ksl < 8; ksl++) {
            int rr = ib * 16 + rA;
            int unit = (ksl * 4 + g) ^ (rr & 7);
            pa[ib][ksl] = *(const bf16x8*)&Pb[rr][unit * 8];
        }

    int dloc = wid * 128;
    for (int dt = 0; dt < 8; dt++) {
        int dl = dloc + dt * 16;
        int d0 = ds * 1024 + dl;
        const unsigned short* vp = Vt + (size_t)(d0 + rA) * 256 + kf;
        bf16x8 vb[8];
        #pragma unroll
        for (int ksl = 0; ksl < 8; ksl++)
            vb[ksl] = *(const bf16x8*)(vp + ksl * 32);
        f32x4 o0 = {0.f, 0.f, 0.f, 0.f}, o1 = {0.f, 0.f, 0.f, 0.f};
        #pragma unroll
        for (int ksl = 0; ksl < 8; ksl++) {
            o0 = __builtin_amdgcn_mfma_f32_16x16x32_bf16(pa[0][ksl], vb[ksl], o0, 0, 0, 0);
            o1 = __builtin_amdgcn_mfma_f32_16x16x32_bf16(pa[1][ksl], vb[ksl], o1, 0, 0, 0);
        }
        int d = d0 + rA;
        int dlr = dl + rA;
        int cpr = d & 7, hh = d >> 3;
        #pragma unroll
        for (int ib = 0; ib < 2; ib++) {
            f32x4 oa = ib ? o1 : o0;
            int ibase = i0 + ib * 16 + g * 4;
            ushort4 pk;
            #pragma unroll
            for (int r = 0; r < 4; r++) {
                int il = ib * 16 + g * 4 + r;
                float qv = b2f(Qs[il][dlr]) * sQ[il];
                ((unsigned short*)&pk)[r] = f2bu(oa[r] + qv);
            }
            *(ushort4*)(G + (size_t)(b * 64 + hd * 8 + cpr) * HW + hh * 256 + ibase) = pk;
        }
    }
}

// ---------------------------------------------------------------------------
// K6: out = PW(out4) + S12 (precomputed x1n+x2n). MFMA for PW.
__global__ __launch_bounds__(256) void k_final(
        const unsigned short* __restrict__ G, const unsigned short* __restrict__ S12g,
        const float* __restrict__ wpw, const float* __restrict__ bpw,
        float* __restrict__ out) {
    __shared__ __align__(16) unsigned short Ws[64][72];
    __shared__ __align__(16) unsigned short Gs[64][260];
    __shared__ __align__(16) unsigned short S12[64][260];
    __shared__ float sb[64];
    int tid = threadIdx.x;
    for (int i = tid; i < 4096; i += 256) Ws[i >> 6][i & 63] = f2bu(wpw[i]);
    if (tid < 64) sb[tid] = bpw[tid];
    int bx = blockIdx.x, b = bx >> 8, h = bx & 255;
    const unsigned short* src = G + (size_t)b * 64 * HW + h * 256;
    const unsigned short* ssrc = S12g + (size_t)b * 64 * HW + h * 256;
    for (int i = tid; i < 2048; i += 256) {
        int c = i >> 5, ch = i & 31;
        uint4 u = *(const uint4*)(src + (size_t)c * HW + ch * 8);
        *(uint2*)&Gs[c][ch * 8]     = make_uint2(u.x, u.y);
        *(uint2*)&Gs[c][ch * 8 + 4] = make_uint2(u.z, u.w);
        uint4 v = *(const uint4*)(ssrc + (size_t)c * HW + ch * 8);
        *(uint2*)&S12[c][ch * 8]     = make_uint2(v.x, v.y);
        *(uint2*)&S12[c][ch * 8 + 4] = make_uint2(v.z, v.w);
    }
    __syncthreads();

    int lane = tid & 63, wv = tid >> 6;
    int rA = lane & 15, g = lane >> 4;
    int p_off = wv * 64;

    f32x4 acc[4][4];
    #pragma unroll
    for (int m = 0; m < 4; m++)
        #pragma unroll
        for (int n = 0; n < 4; n++) acc[m][n] = (f32x4){0.f, 0.f, 0.f, 0.f};

    #pragma unroll
    for (int ks = 0; ks < 2; ks++) {
        int c0 = ks * 32;
        bf16x8 a[4], bb[4];
        #pragma unroll
        for (int m = 0; m < 4; m++)
            a[m] = *(const bf16x8*)&Ws[16 * m + rA][c0 + 8 * g];
        #pragma unroll
        for (int n = 0; n < 4; n++) {
            int p = p_off + 16 * n + rA;
            uint4 bu;
            bu.x = (unsigned)Gs[c0 + 8*g + 0][p] | ((unsigned)Gs[c0 + 8*g + 1][p] << 16);
            bu.y = (unsigned)Gs[c0 + 8*g + 2][p] | ((unsigned)Gs[c0 + 8*g + 3][p] << 16);
            bu.z = (unsigned)Gs[c0 + 8*g + 4][p] | ((unsigned)Gs[c0 + 8*g + 5][p] << 16);
            bu.w = (unsigned)Gs[c0 + 8*g + 6][p] | ((unsigned)Gs[c0 + 8*g + 7][p] << 16);
            bb[n] = *(bf16x8*)&bu;
        }
        #pragma unroll
        for (int m = 0; m < 4; m++)
            #pragma unroll
            for (int n = 0; n < 4; n++)
                acc[m][n] = __builtin_amdgcn_mfma_f32_16x16x32_bf16(a[m], bb[n], acc[m][n], 0, 0, 0);
    }

    #pragma unroll
    for (int m = 0; m < 4; m++) {
        int o0 = 16 * m + 4 * g;
        #pragma unroll
        for (int n = 0; n < 4; n++) {
            int p = p_off + 16 * n + rA;
            #pragma unroll
            for (int r = 0; r < 4; r++) {
                int o = o0 + r;
                out[(size_t)(b * 64 + o) * HW + h * 256 + p] =
                    acc[m][n][r] + sb[o] + b2f(S12[o][p]);
            }
        }
    }
}

// ---------------------------------------------------------------------------
extern "C" void kernel_launch(void* const* d_in, const int* in_sizes, int n_in,
                              void* d_out, int out_size, void* d_ws, size_t ws_size,
                              hipStream_t stream) {
    const float* x1   = (const float*)d_in[0];
    const float* x2   = (const float*)d_in[1];
    const float* ln1w = (const float*)d_in[2];
    const float* ln1b = (const float*)d_in[3];
    const float* ln2w = (const float*)d_in[4];
    const float* ln2b = (const float*)d_in[5];
    const float* bdw  = (const float*)d_in[6];
    const float* wpw  = (const float*)d_in[7];
    const float* bpw  = (const float*)d_in[8];
    const float* kk[12];
    for (int i = 0; i < 12; i++) kk[i] = (const float*)d_in[9 + i];

    char* ws = (char*)d_ws;
    float* wcomb = (float*)ws;              // 5376 floats
    float* bias  = (float*)(ws + 21504);    // 128 floats
    float* invQ  = (float*)(ws + 32768);    // 8192 floats
    float* invK  = (float*)(ws + 65536);    // 8192 floats
    const size_t SMALL = 131072;
    const size_t SZ = 33554432;             // 32 MiB = 16.7M bf16 elements

    // ws slots: S0 = S12 (k_ln -> k_final), S1 = x1n -> Qr (-> k_pv epi),
    // S2 = x2n -> Kr -> out4, S3 = Fv.
    // d_out: dw1|dw2 (k_dw -> k_pw) -> Sp fp32 [0,16.8M) (k_qkt -> k_smx)
    //        + P bf16 @20MiB (k_smx -> k_pv) -> final output (k_final).
    unsigned short* S12b = (unsigned short*)(ws + SMALL);
    unsigned short* S1 = (unsigned short*)(ws + SMALL + SZ);
    unsigned short* S2 = (unsigned short*)(ws + SMALL + 2 * SZ);
    unsigned short* S3 = (unsigned short*)(ws + SMALL + 3 * SZ);
    unsigned short* dw1 = (unsigned short*)d_out;
    unsigned short* dw2 = dw1 + SZ / 2;     // element offset = 16.7M
    float* Sp = (float*)d_out;              // 16.78 MB
    unsigned short* P = (unsigned short*)((char*)d_out + 20971520);  // 4.2 MB

    k_prep<<<1, 64, 0, stream>>>(kk[0], kk[1], kk[2], kk[3], kk[4], kk[5],
                                 kk[6], kk[7], kk[8], kk[9], kk[10], kk[11],
                                 bdw, wcomb, bias);
    k_ln<<<1024, 256, 0, stream>>>(x1, x2, ln1w, ln1b, ln2w, ln2b, S1, S2, S12b);
    k_dw<<<dim3(2048, 2), 256, 0, stream>>>(S1, S2, wcomb, bias, dw1, dw2);
    k_pw<<<dim3(1024, 2), 256, 0, stream>>>(dw1, dw2, wpw, bpw, S1, S2, S3);
    k_norm<<<4096, 256, 0, stream>>>(S1, S2, invQ, invK);
    k_qkt<<<512, 512, 0, stream>>>(S1, S2, Sp);
    k_smx<<<1024, 256, 0, stream>>>(Sp, invQ, invK, P);
    k_pv<<<512, 512, 0, stream>>>(P, S3, S1, invQ, S2);
    k_final<<<1024, 256, 0, stream>>>(S2, S12b, wpw, bpw, (float*)d_out);
}

// Round 9
// 307.829 us; speedup vs baseline: 1.2286x; 1.0449x over previous
//
#include <hip/hip_runtime.h>

#define HW 65536  // 256*256

typedef __bf16 bf16x8 __attribute__((ext_vector_type(8)));
typedef float f32x4 __attribute__((ext_vector_type(4)));

__device__ __forceinline__ float b2f(unsigned short u) {
    return __uint_as_float(((unsigned)u) << 16);
}
__device__ __forceinline__ unsigned short f2bu(float f) {
    unsigned u = __float_as_uint(f);
    return (unsigned short)((u + 0x7FFFu + ((u >> 16) & 1u)) >> 16);
}
// unpack a u32 holding 2 bf16 -> 2 floats (1 VALU op each)
__device__ __forceinline__ void up2(unsigned u, float& lo, float& hi) {
    lo = __uint_as_float(u << 16);
    hi = __uint_as_float(u & 0xFFFF0000u);
}

// ---------------------------------------------------------------------------
// K0: fold 6 depthwise kernels -> combined 21-tap h + 21-tap v per tensor,
// and sum the 6 biases per tensor. wcomb layout: wh1|wv1|wh2|wv2, each 64*21.
__global__ void k_prep(const float* k11, const float* k12, const float* k13,
                       const float* k14, const float* k15, const float* k16,
                       const float* k21, const float* k22, const float* k23,
                       const float* k24, const float* k25, const float* k26,
                       const float* bdw, float* wcomb, float* bias) {
    int c = threadIdx.x;
    if (c >= 64) return;
    float* wh1 = wcomb;
    float* wv1 = wcomb + 1344;
    float* wh2 = wcomb + 2688;
    float* wv2 = wcomb + 4032;
    for (int j = 0; j < 21; j++) {
        wh1[c*21+j] = k13[c*21+j];
        wv1[c*21+j] = k16[c*21+j];
        wh2[c*21+j] = k23[c*21+j];
        wv2[c*21+j] = k26[c*21+j];
    }
    for (int j = 0; j < 11; j++) {
        wh1[c*21+j+5] += k12[c*11+j];
        wv1[c*21+j+5] += k15[c*11+j];
        wh2[c*21+j+5] += k22[c*11+j];
        wv2[c*21+j+5] += k25[c*11+j];
    }
    for (int j = 0; j < 7; j++) {
        wh1[c*21+j+7] += k11[c*7+j];
        wv1[c*21+j+7] += k14[c*7+j];
        wh2[c*21+j+7] += k21[c*7+j];
        wv2[c*21+j+7] += k24[c*7+j];
    }
    float s1 = 0.f, s2 = 0.f;
    for (int i = 0; i < 6; i++) { s1 += bdw[i*64+c]; s2 += bdw[(6+i)*64+c]; }
    bias[c] = s1; bias[64+c] = s2;
}

// ---------------------------------------------------------------------------
// K1: per-pixel LayerNorm of BOTH tensors + S12 = x1n + x2n (bf16).
__global__ __launch_bounds__(256) void k_ln(
        const float* __restrict__ x1, const float* __restrict__ x2,
        const float* __restrict__ w1, const float* __restrict__ b1,
        const float* __restrict__ w2, const float* __restrict__ b2,
        unsigned short* __restrict__ o1, unsigned short* __restrict__ o2,
        unsigned short* __restrict__ s12) {
    int p = blockIdx.x * 256 + threadIdx.x;   // 0..262143
    int b = p >> 16, hw = p & (HW - 1);
    size_t base = (size_t)b * 64 * HW + hw;
    float v[64];
    unsigned n1[32];
    {
        float s = 0.f;
        #pragma unroll
        for (int c = 0; c < 64; c++) { v[c] = x1[base + (size_t)c * HW]; s += v[c]; }
        float mu = s * 0.015625f, s2 = 0.f;
        #pragma unroll
        for (int c = 0; c < 64; c++) { float d = v[c] - mu; s2 += d * d; }
        float rstd = rsqrtf(s2 * 0.015625f + 1e-5f);
        #pragma unroll
        for (int c2 = 0; c2 < 32; c2++) {
            unsigned short lo = f2bu((v[2*c2]   - mu) * rstd * w1[2*c2]   + b1[2*c2]);
            unsigned short hi = f2bu((v[2*c2+1] - mu) * rstd * w1[2*c2+1] + b1[2*c2+1]);
            o1[base + (size_t)(2*c2)   * HW] = lo;
            o1[base + (size_t)(2*c2+1) * HW] = hi;
            n1[c2] = (unsigned)lo | ((unsigned)hi << 16);
        }
    }
    {
        float s = 0.f;
        #pragma unroll
        for (int c = 0; c < 64; c++) { v[c] = x2[base + (size_t)c * HW]; s += v[c]; }
        float mu = s * 0.015625f, s2 = 0.f;
        #pragma unroll
        for (int c = 0; c < 64; c++) { float d = v[c] - mu; s2 += d * d; }
        float rstd = rsqrtf(s2 * 0.015625f + 1e-5f);
        #pragma unroll
        for (int c2 = 0; c2 < 32; c2++) {
            float a2 = (v[2*c2]   - mu) * rstd * w2[2*c2]   + b2[2*c2];
            float b2n = (v[2*c2+1] - mu) * rstd * w2[2*c2+1] + b2[2*c2+1];
            o2[base + (size_t)(2*c2)   * HW] = f2bu(a2);
            o2[base + (size_t)(2*c2+1) * HW] = f2bu(b2n);
            float lo, hi;
            up2(n1[c2], lo, hi);
            s12[base + (size_t)(2*c2)   * HW] = f2bu(lo + a2);
            s12[base + (size_t)(2*c2+1) * HW] = f2bu(hi + b2n);
        }
    }
}

// ---------------------------------------------------------------------------
// K2: combined depthwise conv via MFMA Toeplitz: out = x·Th + Tv·x + bias.
// Th[k][n] = wh[k-n-6] (stored transposed ThT[16][64]); Tv[m][k] = wv[k-m-6].
// Block = (bc, 32-row tile); LDS x-tile 52x320 u16, XOR-swizzled
// (unit ^= (row>>1)&7) so vertical column reads spread across banks.
// Per 16x16 out tile: 4 chained MFMA (2 horiz K-chunks + 2 vert), bias C-init.
__global__ __launch_bounds__(256) void k_dw(
        const unsigned short* __restrict__ in1, const unsigned short* __restrict__ in2,
        const float* __restrict__ wcomb, const float* __restrict__ bias,
        unsigned short* __restrict__ o1, unsigned short* __restrict__ o2) {
    __shared__ __align__(16) unsigned short tileRaw[52 * 320];
    __shared__ __align__(16) unsigned short ThT[16][64];
    __shared__ __align__(16) unsigned short TvA[16][64];
    int which = blockIdx.y;
    const unsigned short* in = which ? in2 : in1;
    unsigned short* o = which ? o2 : o1;
    int bx = blockIdx.x;               // bc*8 + tileid
    int bc = bx >> 3, tileid = bx & 7;
    int c = bc & 63;
    int h0 = tileid * 32;
    int tid = threadIdx.x;

    // build Toeplitz matrices (zero outside band)
    {
        const float* whp = wcomb + which * 2688 + c * 21;
        const float* wvp = whp + 1344;
        for (int i = tid; i < 2048; i += 256) {
            int mat = i >> 10;
            int idx = i & 1023;                 // n*64 + k
            int n = idx >> 6, k = idx & 63;
            int j = k - n - 6;
            float v = (j >= 0 && j < 21) ? (mat ? wvp[j] : whp[j]) : 0.f;
            (mat ? &TvA[0][0] : &ThT[0][0])[idx] = f2bu(v);
        }
    }
    // stage x tile: 52 rows x 40 units (16B each); units 2..33 = data,
    // rest zero. Physical unit = u ^ ((row>>1)&7).
    const unsigned short* src = in + (size_t)bc * HW;
    for (int idx = tid; idx < 52 * 40; idx += 256) {
        int row = idx / 40, u = idx - row * 40;
        int grow = h0 - 10 + row;
        uint4 val = make_uint4(0u, 0u, 0u, 0u);
        if ((unsigned)grow < 256u && u >= 2 && u < 34)
            val = *(const uint4*)(src + grow * 256 + (u - 2) * 8);
        *(uint4*)&tileRaw[row * 320 + ((u ^ ((row >> 1) & 7)) << 3)] = val;
    }
    float bs = bias[which * 64 + c];
    __syncthreads();

    int lane = tid & 63, wid = tid >> 6;
    int rA = lane & 15, g = lane >> 4, kf = g * 8;

    // per-wave constant weight fragments
    bf16x8 thB0 = *(const bf16x8*)&ThT[rA][kf];
    bf16x8 thB1 = *(const bf16x8*)&ThT[rA][32 + kf];
    bf16x8 tvA0 = *(const bf16x8*)&TvA[rA][kf];
    bf16x8 tvA1 = *(const bf16x8*)&TvA[rA][32 + kf];

    int ht = wid & 1, wgrp = wid >> 1;   // wave: h-half ht, w-group wgrp
    for (int t = 0; t < 8; t++) {
        int w0 = (wgrp * 8 + t) * 16;
        int ub = w0 >> 3;
        // horizontal A-frags: A[h][k] = x[h][w0-16+k]; tile col = w0+k
        int hrow = ht * 16 + rA + 10;
        int xh = (hrow >> 1) & 7;
        bf16x8 ax0 = *(const bf16x8*)&tileRaw[hrow * 320 + (((ub + g) ^ xh) << 3)];
        bf16x8 ax1 = *(const bf16x8*)&tileRaw[hrow * 320 + (((ub + 4 + g) ^ xh) << 3)];
        // vertical B-frags: B[k][w], w = w0 + rA, tile row = 16*ht + k - 6
        int uvb = ub + 2 + (rA >> 3);
        int el = rA & 7;
        uint4 bv0, bv1;
        unsigned* pv0 = (unsigned*)&bv0;
        unsigned* pv1 = (unsigned*)&bv1;
        #pragma unroll
        for (int e2 = 0; e2 < 4; e2++) {
            int k0i = kf + 2 * e2;
            int r0 = ht * 16 + k0i - 6;  r0 = r0 < 0 ? 0 : (r0 > 51 ? 51 : r0);
            int r1 = ht * 16 + k0i - 5;  r1 = r1 < 0 ? 0 : (r1 > 51 ? 51 : r1);
            unsigned lo = tileRaw[r0 * 320 + ((uvb ^ ((r0 >> 1) & 7)) << 3) + el];
            unsigned hi = tileRaw[r1 * 320 + ((uvb ^ ((r1 >> 1) & 7)) << 3) + el];
            pv0[e2] = lo | (hi << 16);
            int k1i = 32 + kf + 2 * e2;
            int r2 = ht * 16 + k1i - 6;  r2 = r2 < 0 ? 0 : (r2 > 51 ? 51 : r2);
            int r3 = ht * 16 + k1i - 5;  r3 = r3 < 0 ? 0 : (r3 > 51 ? 51 : r3);
            unsigned lo2 = tileRaw[r2 * 320 + ((uvb ^ ((r2 >> 1) & 7)) << 3) + el];
            unsigned hi2 = tileRaw[r3 * 320 + ((uvb ^ ((r3 >> 1) & 7)) << 3) + el];
            pv1[e2] = lo2 | (hi2 << 16);
        }
        f32x4 acc = {bs, bs, bs, bs};
        acc = __builtin_amdgcn_mfma_f32_16x16x32_bf16(ax0, thB0, acc, 0, 0, 0);
        acc = __builtin_amdgcn_mfma_f32_16x16x32_bf16(ax1, thB1, acc, 0, 0, 0);
        acc = __builtin_amdgcn_mfma_f32_16x16x32_bf16(tvA0, *(bf16x8*)&bv0, acc, 0, 0, 0);
        acc = __builtin_amdgcn_mfma_f32_16x16x32_bf16(tvA1, *(bf16x8*)&bv1, acc, 0, 0, 0);
        // store: lane owns col w0+rA, rows h0 + 16*ht + 4*g + r
        int wc = w0 + rA;
        size_t obase = (size_t)bc * HW + wc;
        #pragma unroll
        for (int r = 0; r < 4; r++) {
            int hh = h0 + ht * 16 + 4 * g + r;
            o[obase + (size_t)hh * 256] = f2bu(acc[r]);
        }
    }
}

// ---------------------------------------------------------------------------
// K3: 1x1 conv (64x64) per pixel, MFMA. Grid x remapped so the 8 blocks
// sharing each 128B output line-group land on the SAME XCD.
__global__ __launch_bounds__(256) void k_pw(
        const unsigned short* __restrict__ in1, const unsigned short* __restrict__ in2,
        const float* __restrict__ wpw, const float* __restrict__ bpw,
        unsigned short* __restrict__ Eq, unsigned short* __restrict__ Fk,
        unsigned short* __restrict__ Fv) {
    __shared__ __align__(16) unsigned short Ws[64][72];
    __shared__ __align__(16) unsigned short Xs[64][260];
    __shared__ float sb[64];
    int tid = threadIdx.x;
    for (int i = tid; i < 4096; i += 256) Ws[i >> 6][i & 63] = f2bu(wpw[i]);
    if (tid < 64) sb[tid] = bpw[tid];
    int which = blockIdx.y;
    const unsigned short* in = which ? in2 : in1;
    int bx = blockIdx.x;
    int b = bx & 3;
    int h = ((bx >> 2) & 31) * 8 + (bx >> 7);
    const unsigned short* src = in + (size_t)b * 64 * HW + h * 256;
    for (int i = tid; i < 2048; i += 256) {
        int c = i >> 5, ch = i & 31;
        uint4 u = *(const uint4*)(src + (size_t)c * HW + ch * 8);
        *(uint2*)&Xs[c][ch * 8]     = make_uint2(u.x, u.y);
        *(uint2*)&Xs[c][ch * 8 + 4] = make_uint2(u.z, u.w);
    }
    __syncthreads();

    int lane = tid & 63, wv = tid >> 6;
    int rA = lane & 15, g = lane >> 4;
    int p_off = wv * 64;

    f32x4 acc[4][4];
    #pragma unroll
    for (int m = 0; m < 4; m++)
        #pragma unroll
        for (int n = 0; n < 4; n++) acc[m][n] = (f32x4){0.f, 0.f, 0.f, 0.f};

    #pragma unroll
    for (int ks = 0; ks < 2; ks++) {
        int c0 = ks * 32;
        bf16x8 a[4], bb[4];
        #pragma unroll
        for (int m = 0; m < 4; m++)
            a[m] = *(const bf16x8*)&Ws[16 * m + rA][c0 + 8 * g];
        #pragma unroll
        for (int n = 0; n < 4; n++) {
            int p = p_off + 16 * n + rA;
            uint4 bu;
            bu.x = (unsigned)Xs[c0 + 8*g + 0][p] | ((unsigned)Xs[c0 + 8*g + 1][p] << 16);
            bu.y = (unsigned)Xs[c0 + 8*g + 2][p] | ((unsigned)Xs[c0 + 8*g + 3][p] << 16);
            bu.z = (unsigned)Xs[c0 + 8*g + 4][p] | ((unsigned)Xs[c0 + 8*g + 5][p] << 16);
            bu.w = (unsigned)Xs[c0 + 8*g + 6][p] | ((unsigned)Xs[c0 + 8*g + 7][p] << 16);
            bb[n] = *(bf16x8*)&bu;
        }
        #pragma unroll
        for (int m = 0; m < 4; m++)
            #pragma unroll
            for (int n = 0; n < 4; n++)
                acc[m][n] = __builtin_amdgcn_mfma_f32_16x16x32_bf16(a[m], bb[n], acc[m][n], 0, 0, 0);
    }

    unsigned short* dst = which ? Fk : Eq;
    size_t b8 = (size_t)b * 8;
    #pragma unroll
    for (int m = 0; m < 4; m++) {
        int o0 = 16 * m + 4 * g;
        int hd = o0 >> 3, cp = o0 & 7;
        #pragma unroll
        for (int n = 0; n < 4; n++) {
            int p = p_off + 16 * n + rA;       // = w
            ushort4 pk;
            #pragma unroll
            for (int r = 0; r < 4; r++)
                ((unsigned short*)&pk)[r] = f2bu(acc[m][n][r] + sb[o0 + r]);
            *(ushort4*)(dst + ((b8 + hd) * 256 + p) * 2048 + h * 8 + cp) = pk;
            if (which) {
                #pragma unroll
                for (int r = 0; r < 4; r++) {
                    int o = o0 + r;
                    Fv[((b8 + (o >> 3)) * 2048 + h * 8 + (o & 7)) * 256 + p] =
                        ((unsigned short*)&pk)[r];
                }
            }
        }
    }
}

// ---------------------------------------------------------------------------
// K4: inverse L2 norms of Q rows and K rows (1 wave per 2048-elem row).
__global__ __launch_bounds__(256) void k_norm(
        const unsigned short* __restrict__ Eq, const unsigned short* __restrict__ Fk,
        float* __restrict__ invQ, float* __restrict__ invK) {
    int lane = threadIdx.x & 63, wid = threadIdx.x >> 6;
    int row = blockIdx.x * 4 + wid;    // 0..16383
    const unsigned short* src = (row < 8192) ? Eq : Fk;
    int r = row & 8191;
    const unsigned short* p = src + (size_t)r * 2048;
    float s = 0.f;
    #pragma unroll
    for (int it = 0; it < 4; it++) {
        uint4 u = *(const uint4*)(p + it * 512 + lane * 8);
        unsigned vals[4] = {u.x, u.y, u.z, u.w};
        #pragma unroll
        for (int e = 0; e < 4; e++) {
            float lo = b2f((unsigned short)(vals[e] & 0xffffu));
            float hi = b2f((unsigned short)(vals[e] >> 16));
            s += lo * lo + hi * hi;
        }
    }
    #pragma unroll
    for (int m = 1; m < 64; m <<= 1) s += __shfl_xor(s, m, 64);
    if (lane == 0) {
        float inv = 1.f / fmaxf(sqrtf(s), 1e-12f);
        (row < 8192 ? invQ : invK)[r] = inv;
    }
}

// ---------------------------------------------------------------------------
// K5a: QK^T partial GEMM. Grid 512 = (itile*2 + ks)*32 + bh (XCD = bh%8).
__global__ __launch_bounds__(512, 4) void k_qkt(
        const unsigned short* __restrict__ Eq, const unsigned short* __restrict__ Fk,
        float* __restrict__ Sp) {
    int bx = blockIdx.x;
    int bh = bx & 31, t2 = bx >> 5;
    int itile = t2 >> 1, ks = t2 & 1;
    int i0 = itile * 32;
    const unsigned short* Q  = Eq + (size_t)bh * 524288 + ks * 1024;
    const unsigned short* Kp = Fk + (size_t)bh * 524288 + ks * 1024;
    int tid = threadIdx.x, lane = tid & 63, wid = tid >> 6;
    int rA = lane & 15, g = lane >> 4, kf = g * 8;

    f32x4 acc[2][2];
    #pragma unroll
    for (int ib = 0; ib < 2; ib++)
        #pragma unroll
        for (int jb = 0; jb < 2; jb++) acc[ib][jb] = (f32x4){0.f, 0.f, 0.f, 0.f};

    const unsigned short* q0  = Q  + (size_t)(i0 + rA) * 2048 + kf;
    const unsigned short* q1  = q0 + 16 * 2048;
    const unsigned short* kr0 = Kp + (size_t)(wid * 32 + rA) * 2048 + kf;
    const unsigned short* kr1 = kr0 + 16 * 2048;
    for (int k0 = 0; k0 < 1024; k0 += 128) {
        bf16x8 a0[4], a1[4], b0[4], b1[4];
        #pragma unroll
        for (int s = 0; s < 4; s++) {
            int kk = k0 + s * 32;
            a0[s] = *(const bf16x8*)(q0 + kk);
            a1[s] = *(const bf16x8*)(q1 + kk);
            b0[s] = *(const bf16x8*)(kr0 + kk);
            b1[s] = *(const bf16x8*)(kr1 + kk);
        }
        #pragma unroll
        for (int s = 0; s < 4; s++) {
            acc[0][0] = __builtin_amdgcn_mfma_f32_16x16x32_bf16(a0[s], b0[s], acc[0][0], 0, 0, 0);
            acc[1][0] = __builtin_amdgcn_mfma_f32_16x16x32_bf16(a1[s], b0[s], acc[1][0], 0, 0, 0);
            acc[0][1] = __builtin_amdgcn_mfma_f32_16x16x32_bf16(a0[s], b1[s], acc[0][1], 0, 0, 0);
            acc[1][1] = __builtin_amdgcn_mfma_f32_16x16x32_bf16(a1[s], b1[s], acc[1][1], 0, 0, 0);
        }
    }
    float* Sb = Sp + (size_t)(ks * 32 + bh) * 65536 + (size_t)i0 * 256;
    #pragma unroll
    for (int ib = 0; ib < 2; ib++)
        #pragma unroll
        for (int jb = 0; jb < 2; jb++)
            #pragma unroll
            for (int r = 0; r < 4; r++)
                Sb[(ib * 16 + g * 4 + r) * 256 + wid * 32 + jb * 16 + rA] = acc[ib][jb][r];
}

// ---------------------------------------------------------------------------
// K5b: softmax. Grid 1024 = rg*32 + bh.
__global__ __launch_bounds__(256) void k_smx(
        const float* __restrict__ Sp, const float* __restrict__ invQ,
        const float* __restrict__ invK, unsigned short* __restrict__ P) {
    __shared__ float sKv[256];
    int bx = blockIdx.x;
    int bh = bx & 31, rg = bx >> 5;
    int tid = threadIdx.x;
    sKv[tid] = invK[bh * 256 + tid];
    __syncthreads();
    int lr = tid >> 5, sub = tid & 31;
    int i = rg * 8 + lr;
    int R = bh * 256 + i;
    const float* p0 = Sp + (size_t)bh * 65536 + i * 256;
    const float* p1 = Sp + (size_t)(32 + bh) * 65536 + i * 256;
    float qs = invQ[R];
    int c0 = sub * 8;
    float4 a0 = *(const float4*)(p0 + c0), a1 = *(const float4*)(p0 + c0 + 4);
    float4 b0 = *(const float4*)(p1 + c0), b1 = *(const float4*)(p1 + c0 + 4);
    float v[8];
    v[0] = (a0.x + b0.x); v[1] = (a0.y + b0.y); v[2] = (a0.z + b0.z); v[3] = (a0.w + b0.w);
    v[4] = (a1.x + b1.x); v[5] = (a1.y + b1.y); v[6] = (a1.z + b1.z); v[7] = (a1.w + b1.w);
    float m = -1e30f;
    #pragma unroll
    for (int e = 0; e < 8; e++) {
        v[e] *= qs * sKv[c0 + e];
        m = fmaxf(m, v[e]);
    }
    #pragma unroll
    for (int msk = 1; msk < 32; msk <<= 1) m = fmaxf(m, __shfl_xor(m, msk, 32));
    float s = 0.f;
    #pragma unroll
    for (int e = 0; e < 8; e++) { v[e] = __expf(v[e] - m); s += v[e]; }
    #pragma unroll
    for (int msk = 1; msk < 32; msk <<= 1) s += __shfl_xor(s, msk, 32);
    float inv = 1.f / s;
    uint4 w;
    w.x = (unsigned)f2bu(v[0] * inv) | ((unsigned)f2bu(v[1] * inv) << 16);
    w.y = (unsigned)f2bu(v[2] * inv) | ((unsigned)f2bu(v[3] * inv) << 16);
    w.z = (unsigned)f2bu(v[4] * inv) | ((unsigned)f2bu(v[5] * inv) << 16);
    w.w = (unsigned)f2bu(v[6] * inv) | ((unsigned)f2bu(v[7] * inv) << 16);
    *(uint4*)(P + (size_t)R * 256 + c0) = w;
}

// ---------------------------------------------------------------------------
// K5c: PV + Qn -> out4 NCHW. Grid 512 = (itile*2 + ds)*32 + bh.
__global__ __launch_bounds__(512, 4) void k_pv(
        const unsigned short* __restrict__ P, const unsigned short* __restrict__ Fv,
        const unsigned short* __restrict__ Eq, const float* __restrict__ invQ,
        unsigned short* __restrict__ G) {
    __shared__ __align__(16) unsigned short Pb[32][256];
    __shared__ __align__(16) unsigned short Qs[32][1024];
    __shared__ float sQ[32];
    int bx = blockIdx.x;
    int bh = bx & 31, t2 = bx >> 5;
    int itile = t2 >> 1, ds = t2 & 1;
    int i0 = itile * 32;
    int b = bh >> 3, hd = bh & 7;
    const unsigned short* Vt = Fv + (size_t)bh * 524288;
    int tid = threadIdx.x, lane = tid & 63, wid = tid >> 6;
    for (int i = tid; i < 1024; i += 512) {
        int r = i >> 5, cu = i & 31;
        uint4 u = *(const uint4*)(P + (size_t)(bh * 256 + i0 + r) * 256 + cu * 8);
        int su = cu ^ (r & 7);
        *(uint4*)&Pb[r][su * 8] = u;
    }
    for (int i = tid; i < 4096; i += 512) {
        int r = i >> 7, cu = i & 127;
        *(uint4*)&Qs[r][cu * 8] =
            *(const uint4*)(Eq + (size_t)(bh * 256 + i0 + r) * 2048 + ds * 1024 + cu * 8);
    }
    if (tid < 32) sQ[tid] = invQ[bh * 256 + i0 + tid];
    __syncthreads();

    int rA = lane & 15, g = lane >> 4, kf = g * 8;

    bf16x8 pa[2][8];
    #pragma unroll
    for (int ib = 0; ib < 2; ib++)
        #pragma unroll
        for (int ksl = 0; ksl < 8; ksl++) {
            int rr = ib * 16 + rA;
            int unit = (ksl * 4 + g) ^ (rr & 7);
            pa[ib][ksl] = *(const bf16x8*)&Pb[rr][unit * 8];
        }

    int dloc = wid * 128;
    for (int dt = 0; dt < 8; dt++) {
        int dl = dloc + dt * 16;
        int d0 = ds * 1024 + dl;
        const unsigned short* vp = Vt + (size_t)(d0 + rA) * 256 + kf;
        bf16x8 vb[8];
        #pragma unroll
        for (int ksl = 0; ksl < 8; ksl++)
            vb[ksl] = *(const bf16x8*)(vp + ksl * 32);
        f32x4 o0 = {0.f, 0.f, 0.f, 0.f}, o1 = {0.f, 0.f, 0.f, 0.f};
        #pragma unroll
        for (int ksl = 0; ksl < 8; ksl++) {
            o0 = __builtin_amdgcn_mfma_f32_16x16x32_bf16(pa[0][ksl], vb[ksl], o0, 0, 0, 0);
            o1 = __builtin_amdgcn_mfma_f32_16x16x32_bf16(pa[1][ksl], vb[ksl], o1, 0, 0, 0);
        }
        int d = d0 + rA;
        int dlr = dl + rA;
        int cpr = d & 7, hh = d >> 3;
        #pragma unroll
        for (int ib = 0; ib < 2; ib++) {
            f32x4 oa = ib ? o1 : o0;
            int ibase = i0 + ib * 16 + g * 4;
            ushort4 pk;
            #pragma unroll
            for (int r = 0; r < 4; r++) {
                int il = ib * 16 + g * 4 + r;
                float qv = b2f(Qs[il][dlr]) * sQ[il];
                ((unsigned short*)&pk)[r] = f2bu(oa[r] + qv);
            }
            *(ushort4*)(G + (size_t)(b * 64 + hd * 8 + cpr) * HW + hh * 256 + ibase) = pk;
        }
    }
}

// ---------------------------------------------------------------------------
// K6: out = PW(out4) + S12 (precomputed x1n+x2n). MFMA for PW.
__global__ __launch_bounds__(256) void k_final(
        const unsigned short* __restrict__ G, const unsigned short* __restrict__ S12g,
        const float* __restrict__ wpw, const float* __restrict__ bpw,
        float* __restrict__ out) {
    __shared__ __align__(16) unsigned short Ws[64][72];
    __shared__ __align__(16) unsigned short Gs[64][260];
    __shared__ __align__(16) unsigned short S12[64][260];
    __shared__ float sb[64];
    int tid = threadIdx.x;
    for (int i = tid; i < 4096; i += 256) Ws[i >> 6][i & 63] = f2bu(wpw[i]);
    if (tid < 64) sb[tid] = bpw[tid];
    int bx = blockIdx.x, b = bx >> 8, h = bx & 255;
    const unsigned short* src = G + (size_t)b * 64 * HW + h * 256;
    const unsigned short* ssrc = S12g + (size_t)b * 64 * HW + h * 256;
    for (int i = tid; i < 2048; i += 256) {
        int c = i >> 5, ch = i & 31;
        uint4 u = *(const uint4*)(src + (size_t)c * HW + ch * 8);
        *(uint2*)&Gs[c][ch * 8]     = make_uint2(u.x, u.y);
        *(uint2*)&Gs[c][ch * 8 + 4] = make_uint2(u.z, u.w);
        uint4 v = *(const uint4*)(ssrc + (size_t)c * HW + ch * 8);
        *(uint2*)&S12[c][ch * 8]     = make_uint2(v.x, v.y);
        *(uint2*)&S12[c][ch * 8 + 4] = make_uint2(v.z, v.w);
    }
    __syncthreads();

    int lane = tid & 63, wv = tid >> 6;
    int rA = lane & 15, g = lane >> 4;
    int p_off = wv * 64;

    f32x4 acc[4][4];
    #pragma unroll
    for (int m = 0; m < 4; m++)
        #pragma unroll
        for (int n = 0; n < 4; n++) acc[m][n] = (f32x4){0.f, 0.f, 0.f, 0.f};

    #pragma unroll
    for (int ks = 0; ks < 2; ks++) {
        int c0 = ks * 32;
        bf16x8 a[4], bb[4];
        #pragma unroll
        for (int m = 0; m < 4; m++)
            a[m] = *(const bf16x8*)&Ws[16 * m + rA][c0 + 8 * g];
        #pragma unroll
        for (int n = 0; n < 4; n++) {
            int p = p_off + 16 * n + rA;
            uint4 bu;
            bu.x = (unsigned)Gs[c0 + 8*g + 0][p] | ((unsigned)Gs[c0 + 8*g + 1][p] << 16);
            bu.y = (unsigned)Gs[c0 + 8*g + 2][p] | ((unsigned)Gs[c0 + 8*g + 3][p] << 16);
            bu.z = (unsigned)Gs[c0 + 8*g + 4][p] | ((unsigned)Gs[c0 + 8*g + 5][p] << 16);
            bu.w = (unsigned)Gs[c0 + 8*g + 6][p] | ((unsigned)Gs[c0 + 8*g + 7][p] << 16);
            bb[n] = *(bf16x8*)&bu;
        }
        #pragma unroll
        for (int m = 0; m < 4; m++)
            #pragma unroll
            for (int n = 0; n < 4; n++)
                acc[m][n] = __builtin_amdgcn_mfma_f32_16x16x32_bf16(a[m], bb[n], acc[m][n], 0, 0, 0);
    }

    #pragma unroll
    for (int m = 0; m < 4; m++) {
        int o0 = 16 * m + 4 * g;
        #pragma unroll
        for (int n = 0; n < 4; n++) {
            int p = p_off + 16 * n + rA;
            #pragma unroll
            for (int r = 0; r < 4; r++) {
                int o = o0 + r;
                out[(size_t)(b * 64 + o) * HW + h * 256 + p] =
                    acc[m][n][r] + sb[o] + b2f(S12[o][p]);
            }
        }
    }
}

// ---------------------------------------------------------------------------
extern "C" void kernel_launch(void* const* d_in, const int* in_sizes, int n_in,
                              void* d_out, int out_size, void* d_ws, size_t ws_size,
                              hipStream_t stream) {
    const float* x1   = (const float*)d_in[0];
    const float* x2   = (const float*)d_in[1];
    const float* ln1w = (const float*)d_in[2];
    const float* ln1b = (const float*)d_in[3];
    const float* ln2w = (const float*)d_in[4];
    const float* ln2b = (const float*)d_in[5];
    const float* bdw  = (const float*)d_in[6];
    const float* wpw  = (const float*)d_in[7];
    const float* bpw  = (const float*)d_in[8];
    const float* kk[12];
    for (int i = 0; i < 12; i++) kk[i] = (const float*)d_in[9 + i];

    char* ws = (char*)d_ws;
    float* wcomb = (float*)ws;              // 5376 floats
    float* bias  = (float*)(ws + 21504);    // 128 floats
    float* invQ  = (float*)(ws + 32768);    // 8192 floats
    float* invK  = (float*)(ws + 65536);    // 8192 floats
    const size_t SMALL = 131072;
    const size_t SZ = 33554432;             // 32 MiB = 16.7M bf16 elements

    unsigned short* S12b = (unsigned short*)(ws + SMALL);
    unsigned short* S1 = (unsigned short*)(ws + SMALL + SZ);
    unsigned short* S2 = (unsigned short*)(ws + SMALL + 2 * SZ);
    unsigned short* S3 = (unsigned short*)(ws + SMALL + 3 * SZ);
    unsigned short* dw1 = (unsigned short*)d_out;
    unsigned short* dw2 = dw1 + SZ / 2;     // element offset = 16.7M
    float* Sp = (float*)d_out;              // 16.78 MB
    unsigned short* P = (unsigned short*)((char*)d_out + 20971520);  // 4.2 MB

    k_prep<<<1, 64, 0, stream>>>(kk[0], kk[1], kk[2], kk[3], kk[4], kk[5],
                                 kk[6], kk[7], kk[8], kk[9], kk[10], kk[11],
                                 bdw, wcomb, bias);
    k_ln<<<1024, 256, 0, stream>>>(x1, x2, ln1w, ln1b, ln2w, ln2b, S1, S2, S12b);
    k_dw<<<dim3(2048, 2), 256, 0, stream>>>(S1, S2, wcomb, bias, dw1, dw2);
    k_pw<<<dim3(1024, 2), 256, 0, stream>>>(dw1, dw2, wpw, bpw, S1, S2, S3);
    k_norm<<<4096, 256, 0, stream>>>(S1, S2, invQ, invK);
    k_qkt<<<512, 512, 0, stream>>>(S1, S2, Sp);
    k_smx<<<1024, 256, 0, stream>>>(Sp, invQ, invK, P);
    k_pv<<<512, 512, 0, stream>>>(P, S3, S1, invQ, S2);
    k_final<<<1024, 256, 0, stream>>>(S2, S12b, wpw, bpw, (float*)d_out);
}

// Round 10
// 263.617 us; speedup vs baseline: 1.4346x; 1.1677x over previous
//
#include <hip/hip_runtime.h>

#define HW 65536  // 256*256

typedef __bf16 bf16x8 __attribute__((ext_vector_type(8)));
typedef float f32x4 __attribute__((ext_vector_type(4)));

__device__ __forceinline__ float b2f(unsigned short u) {
    return __uint_as_float(((unsigned)u) << 16);
}
__device__ __forceinline__ unsigned short f2bu(float f) {
    unsigned u = __float_as_uint(f);
    return (unsigned short)((u + 0x7FFFu + ((u >> 16) & 1u)) >> 16);
}
// unpack a u32 holding 2 bf16 -> 2 floats (1 VALU op each)
__device__ __forceinline__ void up2(unsigned u, float& lo, float& hi) {
    lo = __uint_as_float(u << 16);
    hi = __uint_as_float(u & 0xFFFF0000u);
}

// ---------------------------------------------------------------------------
// K0: fold 6 depthwise kernels -> combined 21-tap h + 21-tap v per tensor.
__global__ void k_prep(const float* k11, const float* k12, const float* k13,
                       const float* k14, const float* k15, const float* k16,
                       const float* k21, const float* k22, const float* k23,
                       const float* k24, const float* k25, const float* k26,
                       const float* bdw, float* wcomb, float* bias) {
    int c = threadIdx.x;
    if (c >= 64) return;
    float* wh1 = wcomb;
    float* wv1 = wcomb + 1344;
    float* wh2 = wcomb + 2688;
    float* wv2 = wcomb + 4032;
    for (int j = 0; j < 21; j++) {
        wh1[c*21+j] = k13[c*21+j];
        wv1[c*21+j] = k16[c*21+j];
        wh2[c*21+j] = k23[c*21+j];
        wv2[c*21+j] = k26[c*21+j];
    }
    for (int j = 0; j < 11; j++) {
        wh1[c*21+j+5] += k12[c*11+j];
        wv1[c*21+j+5] += k15[c*11+j];
        wh2[c*21+j+5] += k22[c*11+j];
        wv2[c*21+j+5] += k25[c*11+j];
    }
    for (int j = 0; j < 7; j++) {
        wh1[c*21+j+7] += k11[c*7+j];
        wv1[c*21+j+7] += k14[c*7+j];
        wh2[c*21+j+7] += k21[c*7+j];
        wv2[c*21+j+7] += k24[c*7+j];
    }
    float s1 = 0.f, s2 = 0.f;
    for (int i = 0; i < 6; i++) { s1 += bdw[i*64+c]; s2 += bdw[(6+i)*64+c]; }
    bias[c] = s1; bias[64+c] = s2;
}

// ---------------------------------------------------------------------------
// K1: per-pixel LayerNorm of BOTH tensors + S12 = x1n + x2n (bf16).
__global__ __launch_bounds__(256) void k_ln(
        const float* __restrict__ x1, const float* __restrict__ x2,
        const float* __restrict__ w1, const float* __restrict__ b1,
        const float* __restrict__ w2, const float* __restrict__ b2,
        unsigned short* __restrict__ o1, unsigned short* __restrict__ o2,
        unsigned short* __restrict__ s12) {
    int p = blockIdx.x * 256 + threadIdx.x;   // 0..262143
    int b = p >> 16, hw = p & (HW - 1);
    size_t base = (size_t)b * 64 * HW + hw;
    float v[64];
    unsigned n1[32];
    {
        float s = 0.f;
        #pragma unroll
        for (int c = 0; c < 64; c++) { v[c] = x1[base + (size_t)c * HW]; s += v[c]; }
        float mu = s * 0.015625f, s2 = 0.f;
        #pragma unroll
        for (int c = 0; c < 64; c++) { float d = v[c] - mu; s2 += d * d; }
        float rstd = rsqrtf(s2 * 0.015625f + 1e-5f);
        #pragma unroll
        for (int c2 = 0; c2 < 32; c2++) {
            unsigned short lo = f2bu((v[2*c2]   - mu) * rstd * w1[2*c2]   + b1[2*c2]);
            unsigned short hi = f2bu((v[2*c2+1] - mu) * rstd * w1[2*c2+1] + b1[2*c2+1]);
            o1[base + (size_t)(2*c2)   * HW] = lo;
            o1[base + (size_t)(2*c2+1) * HW] = hi;
            n1[c2] = (unsigned)lo | ((unsigned)hi << 16);
        }
    }
    {
        float s = 0.f;
        #pragma unroll
        for (int c = 0; c < 64; c++) { v[c] = x2[base + (size_t)c * HW]; s += v[c]; }
        float mu = s * 0.015625f, s2 = 0.f;
        #pragma unroll
        for (int c = 0; c < 64; c++) { float d = v[c] - mu; s2 += d * d; }
        float rstd = rsqrtf(s2 * 0.015625f + 1e-5f);
        #pragma unroll
        for (int c2 = 0; c2 < 32; c2++) {
            float a2 = (v[2*c2]   - mu) * rstd * w2[2*c2]   + b2[2*c2];
            float b2n = (v[2*c2+1] - mu) * rstd * w2[2*c2+1] + b2[2*c2+1];
            o2[base + (size_t)(2*c2)   * HW] = f2bu(a2);
            o2[base + (size_t)(2*c2+1) * HW] = f2bu(b2n);
            float lo, hi;
            up2(n1[c2], lo, hi);
            s12[base + (size_t)(2*c2)   * HW] = f2bu(lo + a2);
            s12[base + (size_t)(2*c2+1) * HW] = f2bu(hi + b2n);
        }
    }
}

// ---------------------------------------------------------------------------
// K2: combined depthwise conv via MFMA Toeplitz (unchanged from R8).
__global__ __launch_bounds__(256) void k_dw(
        const unsigned short* __restrict__ in1, const unsigned short* __restrict__ in2,
        const float* __restrict__ wcomb, const float* __restrict__ bias,
        unsigned short* __restrict__ o1, unsigned short* __restrict__ o2) {
    __shared__ __align__(16) unsigned short tileRaw[52 * 320];
    __shared__ __align__(16) unsigned short ThT[16][64];
    __shared__ __align__(16) unsigned short TvA[16][64];
    int which = blockIdx.y;
    const unsigned short* in = which ? in2 : in1;
    unsigned short* o = which ? o2 : o1;
    int bx = blockIdx.x;
    int bc = bx >> 3, tileid = bx & 7;
    int c = bc & 63;
    int h0 = tileid * 32;
    int tid = threadIdx.x;

    {
        const float* whp = wcomb + which * 2688 + c * 21;
        const float* wvp = whp + 1344;
        for (int i = tid; i < 2048; i += 256) {
            int mat = i >> 10;
            int idx = i & 1023;
            int n = idx >> 6, k = idx & 63;
            int j = k - n - 6;
            float v = (j >= 0 && j < 21) ? (mat ? wvp[j] : whp[j]) : 0.f;
            (mat ? &TvA[0][0] : &ThT[0][0])[idx] = f2bu(v);
        }
    }
    const unsigned short* src = in + (size_t)bc * HW;
    for (int idx = tid; idx < 52 * 40; idx += 256) {
        int row = idx / 40, u = idx - row * 40;
        int grow = h0 - 10 + row;
        uint4 val = make_uint4(0u, 0u, 0u, 0u);
        if ((unsigned)grow < 256u && u >= 2 && u < 34)
            val = *(const uint4*)(src + grow * 256 + (u - 2) * 8);
        *(uint4*)&tileRaw[row * 320 + ((u ^ ((row >> 1) & 7)) << 3)] = val;
    }
    float bs = bias[which * 64 + c];
    __syncthreads();

    int lane = tid & 63, wid = tid >> 6;
    int rA = lane & 15, g = lane >> 4, kf = g * 8;

    bf16x8 thB0 = *(const bf16x8*)&ThT[rA][kf];
    bf16x8 thB1 = *(const bf16x8*)&ThT[rA][32 + kf];
    bf16x8 tvA0 = *(const bf16x8*)&TvA[rA][kf];
    bf16x8 tvA1 = *(const bf16x8*)&TvA[rA][32 + kf];

    int ht = wid & 1, wgrp = wid >> 1;
    for (int t = 0; t < 8; t++) {
        int w0 = (wgrp * 8 + t) * 16;
        int ub = w0 >> 3;
        int hrow = ht * 16 + rA + 10;
        int xh = (hrow >> 1) & 7;
        bf16x8 ax0 = *(const bf16x8*)&tileRaw[hrow * 320 + (((ub + g) ^ xh) << 3)];
        bf16x8 ax1 = *(const bf16x8*)&tileRaw[hrow * 320 + (((ub + 4 + g) ^ xh) << 3)];
        int uvb = ub + 2 + (rA >> 3);
        int el = rA & 7;
        uint4 bv0, bv1;
        unsigned* pv0 = (unsigned*)&bv0;
        unsigned* pv1 = (unsigned*)&bv1;
        #pragma unroll
        for (int e2 = 0; e2 < 4; e2++) {
            int k0i = kf + 2 * e2;
            int r0 = ht * 16 + k0i - 6;  r0 = r0 < 0 ? 0 : (r0 > 51 ? 51 : r0);
            int r1 = ht * 16 + k0i - 5;  r1 = r1 < 0 ? 0 : (r1 > 51 ? 51 : r1);
            unsigned lo = tileRaw[r0 * 320 + ((uvb ^ ((r0 >> 1) & 7)) << 3) + el];
            unsigned hi = tileRaw[r1 * 320 + ((uvb ^ ((r1 >> 1) & 7)) << 3) + el];
            pv0[e2] = lo | (hi << 16);
            int k1i = 32 + kf + 2 * e2;
            int r2 = ht * 16 + k1i - 6;  r2 = r2 < 0 ? 0 : (r2 > 51 ? 51 : r2);
            int r3 = ht * 16 + k1i - 5;  r3 = r3 < 0 ? 0 : (r3 > 51 ? 51 : r3);
            unsigned lo2 = tileRaw[r2 * 320 + ((uvb ^ ((r2 >> 1) & 7)) << 3) + el];
            unsigned hi2 = tileRaw[r3 * 320 + ((uvb ^ ((r3 >> 1) & 7)) << 3) + el];
            pv1[e2] = lo2 | (hi2 << 16);
        }
        f32x4 acc = {bs, bs, bs, bs};
        acc = __builtin_amdgcn_mfma_f32_16x16x32_bf16(ax0, thB0, acc, 0, 0, 0);
        acc = __builtin_amdgcn_mfma_f32_16x16x32_bf16(ax1, thB1, acc, 0, 0, 0);
        acc = __builtin_amdgcn_mfma_f32_16x16x32_bf16(tvA0, *(bf16x8*)&bv0, acc, 0, 0, 0);
        acc = __builtin_amdgcn_mfma_f32_16x16x32_bf16(tvA1, *(bf16x8*)&bv1, acc, 0, 0, 0);
        int wc = w0 + rA;
        size_t obase = (size_t)bc * HW + wc;
        #pragma unroll
        for (int r = 0; r < 4; r++) {
            int hh = h0 + ht * 16 + 4 * g + r;
            o[obase + (size_t)hh * 256] = f2bu(acc[r]);
        }
    }
}

// ---------------------------------------------------------------------------
// K3: 1x1 conv (64x64), MFMA. V now written in kv-tiled layout:
// addr_in_bh = ((d>>4)*32 + (kv>>3))*128 + (d&15)*8 + (kv&7)
// so k_pv's B-fragment loads are 1KB fully contiguous.
__global__ __launch_bounds__(256) void k_pw(
        const unsigned short* __restrict__ in1, const unsigned short* __restrict__ in2,
        const float* __restrict__ wpw, const float* __restrict__ bpw,
        unsigned short* __restrict__ Eq, unsigned short* __restrict__ Fk,
        unsigned short* __restrict__ Fv) {
    __shared__ __align__(16) unsigned short Ws[64][72];
    __shared__ __align__(16) unsigned short Xs[64][260];
    __shared__ float sb[64];
    int tid = threadIdx.x;
    for (int i = tid; i < 4096; i += 256) Ws[i >> 6][i & 63] = f2bu(wpw[i]);
    if (tid < 64) sb[tid] = bpw[tid];
    int which = blockIdx.y;
    const unsigned short* in = which ? in2 : in1;
    int bx = blockIdx.x;
    int b = bx & 3;
    int h = ((bx >> 2) & 31) * 8 + (bx >> 7);
    const unsigned short* src = in + (size_t)b * 64 * HW + h * 256;
    for (int i = tid; i < 2048; i += 256) {
        int c = i >> 5, ch = i & 31;
        uint4 u = *(const uint4*)(src + (size_t)c * HW + ch * 8);
        *(uint2*)&Xs[c][ch * 8]     = make_uint2(u.x, u.y);
        *(uint2*)&Xs[c][ch * 8 + 4] = make_uint2(u.z, u.w);
    }
    __syncthreads();

    int lane = tid & 63, wv = tid >> 6;
    int rA = lane & 15, g = lane >> 4;
    int p_off = wv * 64;

    f32x4 acc[4][4];
    #pragma unroll
    for (int m = 0; m < 4; m++)
        #pragma unroll
        for (int n = 0; n < 4; n++) acc[m][n] = (f32x4){0.f, 0.f, 0.f, 0.f};

    #pragma unroll
    for (int ks = 0; ks < 2; ks++) {
        int c0 = ks * 32;
        bf16x8 a[4], bb[4];
        #pragma unroll
        for (int m = 0; m < 4; m++)
            a[m] = *(const bf16x8*)&Ws[16 * m + rA][c0 + 8 * g];
        #pragma unroll
        for (int n = 0; n < 4; n++) {
            int p = p_off + 16 * n + rA;
            uint4 bu;
            bu.x = (unsigned)Xs[c0 + 8*g + 0][p] | ((unsigned)Xs[c0 + 8*g + 1][p] << 16);
            bu.y = (unsigned)Xs[c0 + 8*g + 2][p] | ((unsigned)Xs[c0 + 8*g + 3][p] << 16);
            bu.z = (unsigned)Xs[c0 + 8*g + 4][p] | ((unsigned)Xs[c0 + 8*g + 5][p] << 16);
            bu.w = (unsigned)Xs[c0 + 8*g + 6][p] | ((unsigned)Xs[c0 + 8*g + 7][p] << 16);
            bb[n] = *(bf16x8*)&bu;
        }
        #pragma unroll
        for (int m = 0; m < 4; m++)
            #pragma unroll
            for (int n = 0; n < 4; n++)
                acc[m][n] = __builtin_amdgcn_mfma_f32_16x16x32_bf16(a[m], bb[n], acc[m][n], 0, 0, 0);
    }

    unsigned short* dst = which ? Fk : Eq;
    size_t b8 = (size_t)b * 8;
    #pragma unroll
    for (int m = 0; m < 4; m++) {
        int o0 = 16 * m + 4 * g;
        int hd = o0 >> 3, cp = o0 & 7;
        #pragma unroll
        for (int n = 0; n < 4; n++) {
            int p = p_off + 16 * n + rA;       // = w = kv
            ushort4 pk;
            #pragma unroll
            for (int r = 0; r < 4; r++)
                ((unsigned short*)&pk)[r] = f2bu(acc[m][n][r] + sb[o0 + r]);
            *(ushort4*)(dst + ((b8 + hd) * 256 + p) * 2048 + h * 8 + cp) = pk;
            if (which) {
                #pragma unroll
                for (int r = 0; r < 4; r++) {
                    int o = o0 + r;
                    int d = h * 8 + (o & 7);
                    size_t vbase = (b8 + (size_t)(o >> 3)) * 524288;
                    int idx = (((d >> 4) * 32 + (p >> 3)) << 7) + ((d & 15) << 3) + (p & 7);
                    Fv[vbase + idx] = ((unsigned short*)&pk)[r];
                }
            }
        }
    }
}

// ---------------------------------------------------------------------------
// K4: inverse L2 norms of Q rows and K rows (1 wave per 2048-elem row).
__global__ __launch_bounds__(256) void k_norm(
        const unsigned short* __restrict__ Eq, const unsigned short* __restrict__ Fk,
        float* __restrict__ invQ, float* __restrict__ invK) {
    int lane = threadIdx.x & 63, wid = threadIdx.x >> 6;
    int row = blockIdx.x * 4 + wid;    // 0..16383
    const unsigned short* src = (row < 8192) ? Eq : Fk;
    int r = row & 8191;
    const unsigned short* p = src + (size_t)r * 2048;
    float s = 0.f;
    #pragma unroll
    for (int it = 0; it < 4; it++) {
        uint4 u = *(const uint4*)(p + it * 512 + lane * 8);
        unsigned vals[4] = {u.x, u.y, u.z, u.w};
        #pragma unroll
        for (int e = 0; e < 4; e++) {
            float lo = b2f((unsigned short)(vals[e] & 0xffffu));
            float hi = b2f((unsigned short)(vals[e] >> 16));
            s += lo * lo + hi * hi;
        }
    }
    #pragma unroll
    for (int m = 1; m < 64; m <<= 1) s += __shfl_xor(s, m, 64);
    if (lane == 0) {
        float inv = 1.f / fmaxf(sqrtf(s), 1e-12f);
        (row < 8192 ? invQ : invK)[r] = inv;
    }
}

// ---------------------------------------------------------------------------
// K5a: QK^T partial GEMM, LDS-staged. Grid 512 = (itile*2 + ks)*32 + bh.
// Per kc (64 of the 1024 k-half): stage Ks[256][64] (32KB) + Qs[32][64] (4KB)
// with full-line coalesced loads + XOR swizzle (u = c8 ^ (row&7)); fragments
// via ds_read_b128 (<=2-way aliasing = free). 8 waves = 2 row-halves x 4
// col-groups, acc[4] each.
__global__ __launch_bounds__(512) void k_qkt(
        const unsigned short* __restrict__ Eq, const unsigned short* __restrict__ Fk,
        float* __restrict__ Sp) {
    __shared__ __align__(16) unsigned short KsRaw[256 * 64];
    __shared__ __align__(16) unsigned short QsRaw[32 * 64];
    int bx = blockIdx.x;
    int bh = bx & 31, t2 = bx >> 5;
    int itile = t2 >> 1, ks = t2 & 1;
    int i0 = itile * 32;
    const unsigned short* Qb = Eq + (size_t)bh * 524288 + ks * 1024;
    const unsigned short* Kb = Fk + (size_t)bh * 524288 + ks * 1024;
    int tid = threadIdx.x, lane = tid & 63, wid = tid >> 6;
    int rA = lane & 15, g = lane >> 4;
    int rt = wid & 1, cg = wid >> 1;

    f32x4 acc[4];
    #pragma unroll
    for (int n = 0; n < 4; n++) acc[n] = (f32x4){0.f, 0.f, 0.f, 0.f};

    for (int kc = 0; kc < 1024; kc += 64) {
        // stage K: 256 rows x 8 chunks(16B); 8 thr/row -> 128B/row full-line
        #pragma unroll
        for (int it = 0; it < 4; it++) {
            int idx = it * 512 + tid;
            int row = idx >> 3, c8 = idx & 7;
            *(uint4*)&KsRaw[row * 64 + ((c8 ^ (row & 7)) << 3)] =
                *(const uint4*)(Kb + (size_t)row * 2048 + kc + c8 * 8);
        }
        // stage Q: 32 rows x 8 chunks
        if (tid < 256) {
            int row = tid >> 3, c8 = tid & 7;
            *(uint4*)&QsRaw[row * 64 + ((c8 ^ (row & 7)) << 3)] =
                *(const uint4*)(Qb + (size_t)(i0 + row) * 2048 + kc + c8 * 8);
        }
        __syncthreads();
        #pragma unroll
        for (int kk = 0; kk < 2; kk++) {
            int c8 = kk * 4 + g;
            int arow = rt * 16 + rA;
            bf16x8 a = *(const bf16x8*)&QsRaw[arow * 64 + ((c8 ^ (arow & 7)) << 3)];
            #pragma unroll
            for (int n = 0; n < 4; n++) {
                int brow = cg * 64 + n * 16 + rA;
                bf16x8 b = *(const bf16x8*)&KsRaw[brow * 64 + ((c8 ^ (brow & 7)) << 3)];
                acc[n] = __builtin_amdgcn_mfma_f32_16x16x32_bf16(a, b, acc[n], 0, 0, 0);
            }
        }
        __syncthreads();
    }
    float* Sb = Sp + (size_t)(ks * 32 + bh) * 65536 + (size_t)i0 * 256;
    #pragma unroll
    for (int n = 0; n < 4; n++)
        #pragma unroll
        for (int r = 0; r < 4; r++)
            Sb[(rt * 16 + g * 4 + r) * 256 + cg * 64 + n * 16 + rA] = acc[n][r];
}

// ---------------------------------------------------------------------------
// K5b: softmax. Grid 1024 = rg*32 + bh.
__global__ __launch_bounds__(256) void k_smx(
        const float* __restrict__ Sp, const float* __restrict__ invQ,
        const float* __restrict__ invK, unsigned short* __restrict__ P) {
    __shared__ float sKv[256];
    int bx = blockIdx.x;
    int bh = bx & 31, rg = bx >> 5;
    int tid = threadIdx.x;
    sKv[tid] = invK[bh * 256 + tid];
    __syncthreads();
    int lr = tid >> 5, sub = tid & 31;
    int i = rg * 8 + lr;
    int R = bh * 256 + i;
    const float* p0 = Sp + (size_t)bh * 65536 + i * 256;
    const float* p1 = Sp + (size_t)(32 + bh) * 65536 + i * 256;
    float qs = invQ[R];
    int c0 = sub * 8;
    float4 a0 = *(const float4*)(p0 + c0), a1 = *(const float4*)(p0 + c0 + 4);
    float4 b0 = *(const float4*)(p1 + c0), b1 = *(const float4*)(p1 + c0 + 4);
    float v[8];
    v[0] = (a0.x + b0.x); v[1] = (a0.y + b0.y); v[2] = (a0.z + b0.z); v[3] = (a0.w + b0.w);
    v[4] = (a1.x + b1.x); v[5] = (a1.y + b1.y); v[6] = (a1.z + b1.z); v[7] = (a1.w + b1.w);
    float m = -1e30f;
    #pragma unroll
    for (int e = 0; e < 8; e++) {
        v[e] *= qs * sKv[c0 + e];
        m = fmaxf(m, v[e]);
    }
    #pragma unroll
    for (int msk = 1; msk < 32; msk <<= 1) m = fmaxf(m, __shfl_xor(m, msk, 32));
    float s = 0.f;
    #pragma unroll
    for (int e = 0; e < 8; e++) { v[e] = __expf(v[e] - m); s += v[e]; }
    #pragma unroll
    for (int msk = 1; msk < 32; msk <<= 1) s += __shfl_xor(s, msk, 32);
    float inv = 1.f / s;
    uint4 w;
    w.x = (unsigned)f2bu(v[0] * inv) | ((unsigned)f2bu(v[1] * inv) << 16);
    w.y = (unsigned)f2bu(v[2] * inv) | ((unsigned)f2bu(v[3] * inv) << 16);
    w.z = (unsigned)f2bu(v[4] * inv) | ((unsigned)f2bu(v[5] * inv) << 16);
    w.w = (unsigned)f2bu(v[6] * inv) | ((unsigned)f2bu(v[7] * inv) << 16);
    *(uint4*)(P + (size_t)R * 256 + c0) = w;
}

// ---------------------------------------------------------------------------
// K5c: PV + Qn -> out4 NCHW. Grid 512 = (itile*2 + ds)*32 + bh. V reads are
// 1KB contiguous thanks to the kv-tiled layout: lane(rA=d&15, g) reads
// Vt[(D*32 + ksl*4 + g)*128 + rA*8 .. +8].
__global__ __launch_bounds__(512, 4) void k_pv(
        const unsigned short* __restrict__ P, const unsigned short* __restrict__ Fv,
        const unsigned short* __restrict__ Eq, const float* __restrict__ invQ,
        unsigned short* __restrict__ G) {
    __shared__ __align__(16) unsigned short Pb[32][256];
    __shared__ __align__(16) unsigned short Qs[32][1024];
    __shared__ float sQ[32];
    int bx = blockIdx.x;
    int bh = bx & 31, t2 = bx >> 5;
    int itile = t2 >> 1, ds = t2 & 1;
    int i0 = itile * 32;
    int b = bh >> 3, hd = bh & 7;
    const unsigned short* Vt = Fv + (size_t)bh * 524288;
    int tid = threadIdx.x, lane = tid & 63, wid = tid >> 6;
    for (int i = tid; i < 1024; i += 512) {
        int r = i >> 5, cu = i & 31;
        uint4 u = *(const uint4*)(P + (size_t)(bh * 256 + i0 + r) * 256 + cu * 8);
        int su = cu ^ (r & 7);
        *(uint4*)&Pb[r][su * 8] = u;
    }
    for (int i = tid; i < 4096; i += 512) {
        int r = i >> 7, cu = i & 127;
        *(uint4*)&Qs[r][cu * 8] =
            *(const uint4*)(Eq + (size_t)(bh * 256 + i0 + r) * 2048 + ds * 1024 + cu * 8);
    }
    if (tid < 32) sQ[tid] = invQ[bh * 256 + i0 + tid];
    __syncthreads();

    int rA = lane & 15, g = lane >> 4;

    bf16x8 pa[2][8];
    #pragma unroll
    for (int ib = 0; ib < 2; ib++)
        #pragma unroll
        for (int ksl = 0; ksl < 8; ksl++) {
            int rr = ib * 16 + rA;
            int unit = (ksl * 4 + g) ^ (rr & 7);
            pa[ib][ksl] = *(const bf16x8*)&Pb[rr][unit * 8];
        }

    int dloc = wid * 128;
    for (int dt = 0; dt < 8; dt++) {
        int dl = dloc + dt * 16;
        int d0 = ds * 1024 + dl;
        int D = d0 >> 4;
        bf16x8 vb[8];
        #pragma unroll
        for (int ksl = 0; ksl < 8; ksl++)
            vb[ksl] = *(const bf16x8*)&Vt[(size_t)(D * 32 + ksl * 4 + g) * 128 + rA * 8];
        f32x4 o0 = {0.f, 0.f, 0.f, 0.f}, o1 = {0.f, 0.f, 0.f, 0.f};
        #pragma unroll
        for (int ksl = 0; ksl < 8; ksl++) {
            o0 = __builtin_amdgcn_mfma_f32_16x16x32_bf16(pa[0][ksl], vb[ksl], o0, 0, 0, 0);
            o1 = __builtin_amdgcn_mfma_f32_16x16x32_bf16(pa[1][ksl], vb[ksl], o1, 0, 0, 0);
        }
        int d = d0 + rA;
        int dlr = dl + rA;
        int cpr = d & 7, hh = d >> 3;
        #pragma unroll
        for (int ib = 0; ib < 2; ib++) {
            f32x4 oa = ib ? o1 : o0;
            int ibase = i0 + ib * 16 + g * 4;
            ushort4 pk;
            #pragma unroll
            for (int r = 0; r < 4; r++) {
                int il = ib * 16 + g * 4 + r;
                float qv = b2f(Qs[il][dlr]) * sQ[il];
                ((unsigned short*)&pk)[r] = f2bu(oa[r] + qv);
            }
            *(ushort4*)(G + (size_t)(b * 64 + hd * 8 + cpr) * HW + hh * 256 + ibase) = pk;
        }
    }
}

// ---------------------------------------------------------------------------
// K6: out = PW(out4) + S12 (precomputed x1n+x2n). MFMA for PW.
__global__ __launch_bounds__(256) void k_final(
        const unsigned short* __restrict__ G, const unsigned short* __restrict__ S12g,
        const float* __restrict__ wpw, const float* __restrict__ bpw,
        float* __restrict__ out) {
    __shared__ __align__(16) unsigned short Ws[64][72];
    __shared__ __align__(16) unsigned short Gs[64][260];
    __shared__ __align__(16) unsigned short S12[64][260];
    __shared__ float sb[64];
    int tid = threadIdx.x;
    for (int i = tid; i < 4096; i += 256) Ws[i >> 6][i & 63] = f2bu(wpw[i]);
    if (tid < 64) sb[tid] = bpw[tid];
    int bx = blockIdx.x, b = bx >> 8, h = bx & 255;
    const unsigned short* src = G + (size_t)b * 64 * HW + h * 256;
    const unsigned short* ssrc = S12g + (size_t)b * 64 * HW + h * 256;
    for (int i = tid; i < 2048; i += 256) {
        int c = i >> 5, ch = i & 31;
        uint4 u = *(const uint4*)(src + (size_t)c * HW + ch * 8);
        *(uint2*)&Gs[c][ch * 8]     = make_uint2(u.x, u.y);
        *(uint2*)&Gs[c][ch * 8 + 4] = make_uint2(u.z, u.w);
        uint4 v = *(const uint4*)(ssrc + (size_t)c * HW + ch * 8);
        *(uint2*)&S12[c][ch * 8]     = make_uint2(v.x, v.y);
        *(uint2*)&S12[c][ch * 8 + 4] = make_uint2(v.z, v.w);
    }
    __syncthreads();

    int lane = tid & 63, wv = tid >> 6;
    int rA = lane & 15, g = lane >> 4;
    int p_off = wv * 64;

    f32x4 acc[4][4];
    #pragma unroll
    for (int m = 0; m < 4; m++)
        #pragma unroll
        for (int n = 0; n < 4; n++) acc[m][n] = (f32x4){0.f, 0.f, 0.f, 0.f};

    #pragma unroll
    for (int ks = 0; ks < 2; ks++) {
        int c0 = ks * 32;
        bf16x8 a[4], bb[4];
        #pragma unroll
        for (int m = 0; m < 4; m++)
            a[m] = *(const bf16x8*)&Ws[16 * m + rA][c0 + 8 * g];
        #pragma unroll
        for (int n = 0; n < 4; n++) {
            int p = p_off + 16 * n + rA;
            uint4 bu;
            bu.x = (unsigned)Gs[c0 + 8*g + 0][p] | ((unsigned)Gs[c0 + 8*g + 1][p] << 16);
            bu.y = (unsigned)Gs[c0 + 8*g + 2][p] | ((unsigned)Gs[c0 + 8*g + 3][p] << 16);
            bu.z = (unsigned)Gs[c0 + 8*g + 4][p] | ((unsigned)Gs[c0 + 8*g + 5][p] << 16);
            bu.w = (unsigned)Gs[c0 + 8*g + 6][p] | ((unsigned)Gs[c0 + 8*g + 7][p] << 16);
            bb[n] = *(bf16x8*)&bu;
        }
        #pragma unroll
        for (int m = 0; m < 4; m++)
            #pragma unroll
            for (int n = 0; n < 4; n++)
                acc[m][n] = __builtin_amdgcn_mfma_f32_16x16x32_bf16(a[m], bb[n], acc[m][n], 0, 0, 0);
    }

    #pragma unroll
    for (int m = 0; m < 4; m++) {
        int o0 = 16 * m + 4 * g;
        #pragma unroll
        for (int n = 0; n < 4; n++) {
            int p = p_off + 16 * n + rA;
            #pragma unroll
            for (int r = 0; r < 4; r++) {
                int o = o0 + r;
                out[(size_t)(b * 64 + o) * HW + h * 256 + p] =
                    acc[m][n][r] + sb[o] + b2f(S12[o][p]);
            }
        }
    }
}

// ---------------------------------------------------------------------------
extern "C" void kernel_launch(void* const* d_in, const int* in_sizes, int n_in,
                              void* d_out, int out_size, void* d_ws, size_t ws_size,
                              hipStream_t stream) {
    const float* x1   = (const float*)d_in[0];
    const float* x2   = (const float*)d_in[1];
    const float* ln1w = (const float*)d_in[2];
    const float* ln1b = (const float*)d_in[3];
    const float* ln2w = (const float*)d_in[4];
    const float* ln2b = (const float*)d_in[5];
    const float* bdw  = (const float*)d_in[6];
    const float* wpw  = (const float*)d_in[7];
    const float* bpw  = (const float*)d_in[8];
    const float* kk[12];
    for (int i = 0; i < 12; i++) kk[i] = (const float*)d_in[9 + i];

    char* ws = (char*)d_ws;
    float* wcomb = (float*)ws;              // 5376 floats
    float* bias  = (float*)(ws + 21504);    // 128 floats
    float* invQ  = (float*)(ws + 32768);    // 8192 floats
    float* invK  = (float*)(ws + 65536);    // 8192 floats
    const size_t SMALL = 131072;
    const size_t SZ = 33554432;             // 32 MiB = 16.7M bf16 elements

    unsigned short* S12b = (unsigned short*)(ws + SMALL);
    unsigned short* S1 = (unsigned short*)(ws + SMALL + SZ);
    unsigned short* S2 = (unsigned short*)(ws + SMALL + 2 * SZ);
    unsigned short* S3 = (unsigned short*)(ws + SMALL + 3 * SZ);
    unsigned short* dw1 = (unsigned short*)d_out;
    unsigned short* dw2 = dw1 + SZ / 2;     // element offset = 16.7M
    float* Sp = (float*)d_out;              // 16.78 MB
    unsigned short* P = (unsigned short*)((char*)d_out + 20971520);  // 4.2 MB

    k_prep<<<1, 64, 0, stream>>>(kk[0], kk[1], kk[2], kk[3], kk[4], kk[5],
                                 kk[6], kk[7], kk[8], kk[9], kk[10], kk[11],
                                 bdw, wcomb, bias);
    k_ln<<<1024, 256, 0, stream>>>(x1, x2, ln1w, ln1b, ln2w, ln2b, S1, S2, S12b);
    k_dw<<<dim3(2048, 2), 256, 0, stream>>>(S1, S2, wcomb, bias, dw1, dw2);
    k_pw<<<dim3(1024, 2), 256, 0, stream>>>(dw1, dw2, wpw, bpw, S1, S2, S3);
    k_norm<<<4096, 256, 0, stream>>>(S1, S2, invQ, invK);
    k_qkt<<<512, 512, 0, stream>>>(S1, S2, Sp);
    k_smx<<<1024, 256, 0, stream>>>(Sp, invQ, invK, P);
    k_pv<<<512, 512, 0, stream>>>(P, S3, S1, invQ, S2);
    k_final<<<1024, 256, 0, stream>>>(S2, S12b, wpw, bpw, (float*)d_out);
}